// Round 2
// baseline (6767.798 us; speedup 1.0000x reference)
//
#include <hip/hip_runtime.h>
#include <hip/hip_bf16.h>

// Problem constants
#define B_    32
#define L_    200
#define H_    256
#define NH_   4
#define D_    64
#define C_    16
#define SCALE_ 0.125f
#define EPS_  1e-12f

struct ProjArgs {
  const float* X[9];
  const float* W[9];
  const float* Bi[9];
};

// ---------------------------------------------------------------------------
// Kernel 1: 9 projections  out = X @ W + bias.
// Q -> Qbuf[((bh*4+cq)*200+l)*64+d]
// K -> Kt[mat][d>>2][l][d&3]   (mat = bh*4+ck), i.e. mat*12800+(d>>2)*800+l*4+(d&3)
// V -> Vbuf[(bh*200+l)*64+d]
// ---------------------------------------------------------------------------
__global__ __launch_bounds__(256) void proj_kernel(ProjArgs pa,
                                                   float* __restrict__ Qbuf,
                                                   float* __restrict__ Ktb,
                                                   float* __restrict__ Vbuf) {
  const int z = blockIdx.z;
  const float* __restrict__ X    = pa.X[z];
  const float* __restrict__ W    = pa.W[z];
  const float* __restrict__ bias = pa.Bi[z];

  __shared__ float As[16][65];
  __shared__ float Bs[16][64];

  const int tid = threadIdx.x;
  const int tx = tid & 15, ty = tid >> 4;
  const int row0 = blockIdx.y * 64, col0 = blockIdx.x * 64;

  float acc[4][4] = {};

  for (int k0 = 0; k0 < 256; k0 += 16) {
    for (int i = tid; i < 1024; i += 256) {
      int m = i >> 4, k = i & 15;
      As[k][m] = X[(row0 + m) * 256 + k0 + k];
    }
    for (int i = tid; i < 1024; i += 256) {
      int k = i >> 6, n = i & 63;
      Bs[k][n] = W[(k0 + k) * 256 + col0 + n];
    }
    __syncthreads();
#pragma unroll
    for (int k = 0; k < 16; ++k) {
      float a0 = As[k][ty * 4 + 0];
      float a1 = As[k][ty * 4 + 1];
      float a2 = As[k][ty * 4 + 2];
      float a3 = As[k][ty * 4 + 3];
      float4 bv = *(const float4*)&Bs[k][tx * 4];
      acc[0][0] += a0 * bv.x; acc[0][1] += a0 * bv.y; acc[0][2] += a0 * bv.z; acc[0][3] += a0 * bv.w;
      acc[1][0] += a1 * bv.x; acc[1][1] += a1 * bv.y; acc[1][2] += a1 * bv.z; acc[1][3] += a1 * bv.w;
      acc[2][0] += a2 * bv.x; acc[2][1] += a2 * bv.y; acc[2][2] += a2 * bv.z; acc[2][3] += a2 * bv.w;
      acc[3][0] += a3 * bv.x; acc[3][1] += a3 * bv.y; acc[3][2] += a3 * bv.z; acc[3][3] += a3 * bv.w;
    }
    __syncthreads();
  }

#pragma unroll
  for (int i = 0; i < 4; ++i) {
    int r = row0 + ty * 4 + i;
    int b = r / 200, l = r % 200;
#pragma unroll
    for (int j = 0; j < 4; ++j) {
      int n = col0 + tx * 4 + j;
      float v = acc[i][j] + bias[n];
      int h = n >> 6, d = n & 63;
      int bh = b * 4 + h;
      if (z < 4) {
        Qbuf[(((size_t)bh * 4 + z) * 200 + l) * 64 + d] = v;
      } else if (z < 8) {
        int mat = bh * 4 + (z - 4);
        Ktb[(size_t)mat * 12800 + (d >> 2) * 800 + l * 4 + (d & 3)] = v;
      } else {
        Vbuf[((size_t)bh * 200 + l) * 64 + d] = v;
      }
    }
  }
}

// ---------------------------------------------------------------------------
// Kernel 2: KW[mat][n][d] = sum_m Wf1[m][n] * K[mat][m][d], stored transposed:
// KWt[mat*12800 + (d>>2)*800 + n*4 + (d&3)].  mat = bh*4+ck (512 matrices).
// Block: 64n x 64d tile; grid (4 ntiles, 512 mats).
// ---------------------------------------------------------------------------
__global__ __launch_bounds__(256) void kw_kernel(const float* __restrict__ Wf1,
                                                 const float* __restrict__ Ktb,
                                                 float* __restrict__ KWt) {
  const int mat = blockIdx.y;
  const int n0 = blockIdx.x * 64;

  __shared__ float As[16][65];   // [m][n]
  __shared__ float Bs[16][64];   // [m][d]

  const int tid = threadIdx.x;
  const int tx = tid & 15, ty = tid >> 4;

  float acc[4][4] = {};

  for (int m0 = 0; m0 < 200; m0 += 16) {
    for (int i = tid; i < 1024; i += 256) {
      int k = i >> 6, n = i & 63;
      int m = m0 + k, nn = n0 + n;
      As[k][n] = (m < 200 && nn < 200) ? Wf1[m * 200 + nn] : 0.f;
    }
    for (int i = tid; i < 1024; i += 256) {
      int k = i >> 6, d = i & 63;
      int m = m0 + k;
      Bs[k][d] = (m < 200)
          ? Ktb[(size_t)mat * 12800 + (d >> 2) * 800 + m * 4 + (d & 3)]
          : 0.f;
    }
    __syncthreads();
#pragma unroll
    for (int k = 0; k < 16; ++k) {
      float a0 = As[k][ty * 4 + 0];
      float a1 = As[k][ty * 4 + 1];
      float a2 = As[k][ty * 4 + 2];
      float a3 = As[k][ty * 4 + 3];
      float4 bv = *(const float4*)&Bs[k][tx * 4];
      acc[0][0] += a0 * bv.x; acc[0][1] += a0 * bv.y; acc[0][2] += a0 * bv.z; acc[0][3] += a0 * bv.w;
      acc[1][0] += a1 * bv.x; acc[1][1] += a1 * bv.y; acc[1][2] += a1 * bv.z; acc[1][3] += a1 * bv.w;
      acc[2][0] += a2 * bv.x; acc[2][1] += a2 * bv.y; acc[2][2] += a2 * bv.z; acc[2][3] += a2 * bv.w;
      acc[3][0] += a3 * bv.x; acc[3][1] += a3 * bv.y; acc[3][2] += a3 * bv.z; acc[3][3] += a3 * bv.w;
    }
    __syncthreads();
  }

#pragma unroll
  for (int i = 0; i < 4; ++i) {
    int n = n0 + ty * 4 + i;
    if (n < 200) {
#pragma unroll
      for (int j = 0; j < 4; ++j) {
        int d = tx * 4 + j;
        KWt[(size_t)mat * 12800 + (d >> 2) * 800 + n * 4 + (d & 3)] = acc[i][j];
      }
    }
  }
}

// ---------------------------------------------------------------------------
// Kernel 3: fused attention core per (b,h,lt) with LT=8 query rows.
// energy via q.KW (K=64 dots), channel softmax, qw = w-weighted q,
// attn row via qw.K, masked row softmax, PV.
// ---------------------------------------------------------------------------
__global__ __launch_bounds__(256) void fused_attn_kernel(
    const float* __restrict__ Qbuf, const float* __restrict__ Ktb,
    const float* __restrict__ KWt, const float* __restrict__ Vbuf,
    const float* __restrict__ mask, const float* __restrict__ bf1,
    const float* __restrict__ Wf2, const float* __restrict__ bf2,
    float* __restrict__ Ctx) {
  const int lt = blockIdx.x;          // 0..24
  const int h = blockIdx.y, b = blockIdx.z;
  const int bh = b * 4 + h;
  const int l0 = lt * 8;
  const int tid = threadIdx.x;

  __shared__ float Qs[8][4][64];            // [l][cq][d]  8 KB (reused as ctxp)
  __shared__ float qw_sh[4][8][64];         // [ck][l][d]  8 KB
  __shared__ float att_sh[8][208];          // 6.66 KB
  __shared__ float epart_sh[4][2][4][16];   // [wave][lh][lp][c] 2 KB
  __shared__ float wght_sh[8][16];
  __shared__ float rinv_sh[8];

  // ---- phase 1: stage Q (8 l x 4 cq x 64 d)
  for (int i = tid; i < 2048; i += 256) {
    int l = i >> 8, cq = (i >> 6) & 3, d = i & 63;
    Qs[l][cq][d] = Qbuf[(((size_t)bh * 4 + cq) * 200 + l0 + l) * 64 + d];
  }
  __syncthreads();

  // ---- phase 2: E_pre + energy partials.  thread owns column n.
  const int n = (tid < 200) ? tid : 199;
  const float wf2n = (tid < 200) ? Wf2[n] : 0.f;
  const float bf1n = bf1[n];
  const float* KWbase = KWt + (size_t)(bh * 4) * 12800;

  for (int lh = 0; lh < 2; ++lh) {
    float eacc[4][16];
#pragma unroll
    for (int lp = 0; lp < 4; ++lp)
#pragma unroll
      for (int c = 0; c < 16; ++c) eacc[lp][c] = 0.f;

#pragma unroll
    for (int ck = 0; ck < 4; ++ck) {
      float dot[4][4] = {};
#pragma unroll
      for (int dc = 0; dc < 4; ++dc) {   // 16 d's per chunk
        float4 kw[4];
#pragma unroll
        for (int u = 0; u < 4; ++u)
          kw[u] = *(const float4*)&KWbase[(size_t)ck * 12800 + (dc * 4 + u) * 800 + n * 4];
#pragma unroll
        for (int lp = 0; lp < 4; ++lp) {
#pragma unroll
          for (int cq = 0; cq < 4; ++cq) {
            const float* qp = &Qs[lh * 4 + lp][cq][dc * 16];
            float4 q0 = ((const float4*)qp)[0];
            float4 q1 = ((const float4*)qp)[1];
            float4 q2 = ((const float4*)qp)[2];
            float4 q3 = ((const float4*)qp)[3];
            dot[lp][cq] += q0.x * kw[0].x + q0.y * kw[0].y + q0.z * kw[0].z + q0.w * kw[0].w
                         + q1.x * kw[1].x + q1.y * kw[1].y + q1.z * kw[1].z + q1.w * kw[1].w
                         + q2.x * kw[2].x + q2.y * kw[2].y + q2.z * kw[2].z + q2.w * kw[2].w
                         + q3.x * kw[3].x + q3.y * kw[3].y + q3.z * kw[3].z + q3.w * kw[3].w;
          }
        }
      }
#pragma unroll
      for (int lp = 0; lp < 4; ++lp)
#pragma unroll
        for (int cq = 0; cq < 4; ++cq)
          eacc[lp][cq * 4 + ck] = fmaxf(dot[lp][cq] + bf1n, 0.f) * wf2n;
    }

    // reduce over n (64 lanes of this wave)
#pragma unroll
    for (int lp = 0; lp < 4; ++lp) {
#pragma unroll
      for (int c = 0; c < 16; ++c) {
        float v = eacc[lp][c];
        v += __shfl_xor(v, 32);
        v += __shfl_xor(v, 16);
        v += __shfl_xor(v, 8);
        v += __shfl_xor(v, 4);
        v += __shfl_xor(v, 2);
        v += __shfl_xor(v, 1);
        if ((tid & 63) == 0) epart_sh[tid >> 6][lh][lp][c] = v;
      }
    }
  }
  __syncthreads();

  // ---- phase 3: finish energy (sum over 4 waves) + channel softmax (16)
  if (tid < 128) {
    int l = tid >> 4, c = tid & 15;
    float e = bf2[0];
#pragma unroll
    for (int w = 0; w < 4; ++w) e += epart_sh[w][l >> 2][l & 3][c];
    float mx = e;
    mx = fmaxf(mx, __shfl_xor(mx, 8));
    mx = fmaxf(mx, __shfl_xor(mx, 4));
    mx = fmaxf(mx, __shfl_xor(mx, 2));
    mx = fmaxf(mx, __shfl_xor(mx, 1));
    float ex = __expf(e - mx);
    float s = ex;
    s += __shfl_xor(s, 8);
    s += __shfl_xor(s, 4);
    s += __shfl_xor(s, 2);
    s += __shfl_xor(s, 1);
    wght_sh[l][c] = ex / s;
  }
  __syncthreads();

  // ---- phase 4: qw[ck][l][d] = sum_cq w[l][cq*4+ck] * q[l][cq][d]
  for (int i = tid; i < 2048; i += 256) {
    int ck = i >> 9, l = (i >> 6) & 7, d = i & 63;
    float s = wght_sh[l][0 * 4 + ck] * Qs[l][0][d]
            + wght_sh[l][1 * 4 + ck] * Qs[l][1][d]
            + wght_sh[l][2 * 4 + ck] * Qs[l][2][d]
            + wght_sh[l][3 * 4 + ck] * Qs[l][3][d];
    qw_sh[ck][l][d] = s;
  }
  __syncthreads();

  // ---- phase 5: attn[l][m] = sum_ck qw[l][ck] . K[ck][m] ; thread owns m.
  {
    const int m = (tid < 200) ? tid : 199;
    const float* Ktbase = Ktb + (size_t)(bh * 4) * 12800;
    float katt[8] = {0.f, 0.f, 0.f, 0.f, 0.f, 0.f, 0.f, 0.f};
#pragma unroll
    for (int ck = 0; ck < 4; ++ck) {
      float4 kreg[16];
#pragma unroll
      for (int u = 0; u < 16; ++u)
        kreg[u] = *(const float4*)&Ktbase[(size_t)ck * 12800 + u * 800 + m * 4];
#pragma unroll
      for (int l = 0; l < 8; ++l) {
        float s = 0.f;
#pragma unroll
        for (int u = 0; u < 16; ++u) {
          float4 q = *(const float4*)&qw_sh[ck][l][u * 4];
          s += q.x * kreg[u].x + q.y * kreg[u].y + q.z * kreg[u].z + q.w * kreg[u].w;
        }
        katt[l] += s;
      }
    }
    if (tid < 200) {
#pragma unroll
      for (int l = 0; l < 8; ++l)
        att_sh[l][m] = katt[l] * SCALE_ + mask[(size_t)(l0 + l) * 200 + m];
    }
  }
  __syncthreads();

  // ---- phase 6: masked row softmax over m (store unnormalized exp + 1/sum)
  {
    int l = tid >> 5, j = tid & 31;
    float mx = -3.0e38f;
    for (int m = j; m < 200; m += 32) mx = fmaxf(mx, att_sh[l][m]);
    mx = fmaxf(mx, __shfl_xor(mx, 16));
    mx = fmaxf(mx, __shfl_xor(mx, 8));
    mx = fmaxf(mx, __shfl_xor(mx, 4));
    mx = fmaxf(mx, __shfl_xor(mx, 2));
    mx = fmaxf(mx, __shfl_xor(mx, 1));
    float sum = 0.f;
    for (int m = j; m < 200; m += 32) {
      float ex = __expf(att_sh[l][m] - mx);
      att_sh[l][m] = ex;
      sum += ex;
    }
    sum += __shfl_xor(sum, 16);
    sum += __shfl_xor(sum, 8);
    sum += __shfl_xor(sum, 4);
    sum += __shfl_xor(sum, 2);
    sum += __shfl_xor(sum, 1);
    if (j == 0) rinv_sh[l] = 1.f / sum;
  }
  __syncthreads();

  // ---- phase 7: PV.  thread (d, mg) accumulates 8 l over 50 m.
  {
    int d = tid & 63, mg = tid >> 6;
    float acc[8] = {0.f, 0.f, 0.f, 0.f, 0.f, 0.f, 0.f, 0.f};
    const float* Vb = Vbuf + (size_t)bh * 200 * 64;
    for (int m = mg * 50; m < mg * 50 + 50; ++m) {
      float v = Vb[m * 64 + d];
#pragma unroll
      for (int l = 0; l < 8; ++l) acc[l] += att_sh[l][m] * v;
    }
    float* ctxp = &Qs[0][0][0];   // Qs is dead; reuse as [mg][l][d]
    __syncthreads();              // ensure all phase-4 readers of Qs done (already past) & writers ordered
#pragma unroll
    for (int l = 0; l < 8; ++l) ctxp[(mg * 8 + l) * 64 + d] = acc[l];
  }
  __syncthreads();

  // ---- phase 8: combine partials, normalize, write ctx
  {
    const float* ctxp = &Qs[0][0][0];
    for (int i = tid; i < 512; i += 256) {
      int l = i >> 6, d = i & 63;
      float c = (ctxp[(0 * 8 + l) * 64 + d] + ctxp[(1 * 8 + l) * 64 + d] +
                 ctxp[(2 * 8 + l) * 64 + d] + ctxp[(3 * 8 + l) * 64 + d]) * rinv_sh[l];
      Ctx[((size_t)b * 200 + l0 + l) * 256 + h * 64 + d] = c;
    }
  }
}

// ---------------------------------------------------------------------------
// Kernel 4: x = ctx @ Wd + bd + input; LayerNorm(x). One block per row.
// ---------------------------------------------------------------------------
__global__ __launch_bounds__(256) void out_ln_kernel(
    const float* __restrict__ Ctx, const float* __restrict__ Wd,
    const float* __restrict__ bd, const float* __restrict__ input,
    const float* __restrict__ gamma, const float* __restrict__ beta,
    float* __restrict__ out) {
  const int row = blockIdx.x;
  const int n = threadIdx.x;
  __shared__ float c_sh[256];
  __shared__ float red[4];

  c_sh[n] = Ctx[(size_t)row * 256 + n];
  __syncthreads();

  float acc = bd[n];
#pragma unroll 8
  for (int k = 0; k < 256; ++k) acc += c_sh[k] * Wd[k * 256 + n];
  float x = acc + input[(size_t)row * 256 + n];

  float s = x;
#pragma unroll
  for (int o = 32; o; o >>= 1) s += __shfl_xor(s, o);
  if ((n & 63) == 0) red[n >> 6] = s;
  __syncthreads();
  float mu = (red[0] + red[1] + red[2] + red[3]) * (1.f / 256.f);
  __syncthreads();
  float dv = (x - mu) * (x - mu);
#pragma unroll
  for (int o = 32; o; o >>= 1) dv += __shfl_xor(dv, o);
  if ((n & 63) == 0) red[n >> 6] = dv;
  __syncthreads();
  float var = (red[0] + red[1] + red[2] + red[3]) * (1.f / 256.f);

  out[(size_t)row * 256 + n] = (x - mu) * rsqrtf(var + EPS_) * gamma[n] + beta[n];
}

// ---------------------------------------------------------------------------
extern "C" void kernel_launch(void* const* d_in, const int* in_sizes, int n_in,
                              void* d_out, int out_size, void* d_ws, size_t ws_size,
                              hipStream_t stream) {
  const float* input = (const float*)d_in[0];
  const float* attrt = (const float*)d_in[1];   // (F,B,L,1,H)
  const float* pos   = (const float*)d_in[2];
  const float* mask  = (const float*)d_in[3];
  const float* Wq  = (const float*)d_in[4];   const float* bq  = (const float*)d_in[5];
  const float* Wk  = (const float*)d_in[6];   const float* bk  = (const float*)d_in[7];
  const float* Wv  = (const float*)d_in[8];   const float* bv  = (const float*)d_in[9];
  const float* Wqp = (const float*)d_in[10];  const float* bqp = (const float*)d_in[11];
  const float* Wkp = (const float*)d_in[12];  const float* bkp = (const float*)d_in[13];
  const float* Wq_a = (const float*)d_in[16]; const float* bq_a = (const float*)d_in[17];
  const float* Wk_a = (const float*)d_in[18]; const float* bk_a = (const float*)d_in[19];
  const float* Wf1 = (const float*)d_in[22];  const float* bf1 = (const float*)d_in[23];
  const float* Wf2 = (const float*)d_in[24];  const float* bf2 = (const float*)d_in[25];
  const float* Wd  = (const float*)d_in[26];  const float* bd  = (const float*)d_in[27];
  const float* gamma = (const float*)d_in[28]; const float* beta = (const float*)d_in[29];

  const float* attr0 = attrt;
  const float* attr1 = attrt + (size_t)B_ * L_ * H_;

  float* ws = (float*)d_ws;
  float* Qbuf = ws;                   // 6,553,600 floats
  float* Ktb  = Qbuf + 6553600;       // 6,553,600
  float* KWt  = Ktb + 6553600;        // 6,553,600
  float* Vbuf = KWt + 6553600;        // 1,638,400
  float* Ctx  = Vbuf + 1638400;       // 1,638,400  (total ~91.8 MiB)

  ProjArgs pa;
  // Q channels: 0=q_i, 1=q_p, 2=q_a0, 3=q_a1
  pa.X[0] = input; pa.W[0] = Wq;              pa.Bi[0] = bq;
  pa.X[1] = pos;   pa.W[1] = Wqp;             pa.Bi[1] = bqp;
  pa.X[2] = attr0; pa.W[2] = Wq_a;            pa.Bi[2] = bq_a;
  pa.X[3] = attr1; pa.W[3] = Wq_a + 65536;    pa.Bi[3] = bq_a + 256;
  // K channels: 0=k_i, 1=k_a0, 2=k_a1, 3=k_p
  pa.X[4] = input; pa.W[4] = Wk;              pa.Bi[4] = bk;
  pa.X[5] = attr0; pa.W[5] = Wk_a;            pa.Bi[5] = bk_a;
  pa.X[6] = attr1; pa.W[6] = Wk_a + 65536;    pa.Bi[6] = bk_a + 256;
  pa.X[7] = pos;   pa.W[7] = Wkp;             pa.Bi[7] = bkp;
  // V
  pa.X[8] = input; pa.W[8] = Wv;              pa.Bi[8] = bv;

  proj_kernel<<<dim3(4, 100, 9), dim3(256), 0, stream>>>(pa, Qbuf, Ktb, Vbuf);
  kw_kernel<<<dim3(4, 512), dim3(256), 0, stream>>>(Wf1, Ktb, KWt);
  fused_attn_kernel<<<dim3(25, 4, 32), dim3(256), 0, stream>>>(
      Qbuf, Ktb, KWt, Vbuf, mask, bf1, Wf2, bf2, Ctx);
  out_ln_kernel<<<dim3(6400), dim3(256), 0, stream>>>(Ctx, Wd, bd, input,
                                                      gamma, beta, (float*)d_out);
}

// Round 3
// 855.507 us; speedup vs baseline: 7.9109x; 7.9109x over previous
//
#include <hip/hip_runtime.h>
#include <hip/hip_bf16.h>

// Problem constants
#define B_    32
#define L_    200
#define H_    256
#define NH_   4
#define D_    64
#define SCALE_ 0.125f
#define EPS_  1e-12f

struct ProjArgs {
  const float* X[9];
  const float* W[9];
  const float* Bi[9];
};

// ---------------------------------------------------------------------------
// Kernel 1: 9 projections  out = X @ W + bias.
// Q -> Qbuf[((bh*4+cq)*200+l)*64+d]
// K -> Ktb[mat*12800 + (d>>2)*800 + l*4 + (d&3)]   (mat = bh*4+ck)
// V -> Vbuf[(bh*200+l)*64+d]
// ---------------------------------------------------------------------------
__global__ __launch_bounds__(256) void proj_kernel(ProjArgs pa,
                                                   float* __restrict__ Qbuf,
                                                   float* __restrict__ Ktb,
                                                   float* __restrict__ Vbuf) {
  const int z = blockIdx.z;
  const float* __restrict__ X    = pa.X[z];
  const float* __restrict__ W    = pa.W[z];
  const float* __restrict__ bias = pa.Bi[z];

  __shared__ float As[16][65];
  __shared__ float Bs[16][64];

  const int tid = threadIdx.x;
  const int tx = tid & 15, ty = tid >> 4;
  const int row0 = blockIdx.y * 64, col0 = blockIdx.x * 64;

  float acc[4][4] = {};

  for (int k0 = 0; k0 < 256; k0 += 16) {
    for (int i = tid; i < 1024; i += 256) {
      int m = i >> 4, k = i & 15;
      As[k][m] = X[(row0 + m) * 256 + k0 + k];
    }
    for (int i = tid; i < 1024; i += 256) {
      int k = i >> 6, n = i & 63;
      Bs[k][n] = W[(k0 + k) * 256 + col0 + n];
    }
    __syncthreads();
#pragma unroll
    for (int k = 0; k < 16; ++k) {
      float a0 = As[k][ty * 4 + 0];
      float a1 = As[k][ty * 4 + 1];
      float a2 = As[k][ty * 4 + 2];
      float a3 = As[k][ty * 4 + 3];
      float4 bv = *(const float4*)&Bs[k][tx * 4];
      acc[0][0] += a0 * bv.x; acc[0][1] += a0 * bv.y; acc[0][2] += a0 * bv.z; acc[0][3] += a0 * bv.w;
      acc[1][0] += a1 * bv.x; acc[1][1] += a1 * bv.y; acc[1][2] += a1 * bv.z; acc[1][3] += a1 * bv.w;
      acc[2][0] += a2 * bv.x; acc[2][1] += a2 * bv.y; acc[2][2] += a2 * bv.z; acc[2][3] += a2 * bv.w;
      acc[3][0] += a3 * bv.x; acc[3][1] += a3 * bv.y; acc[3][2] += a3 * bv.z; acc[3][3] += a3 * bv.w;
    }
    __syncthreads();
  }

#pragma unroll
  for (int i = 0; i < 4; ++i) {
    int r = row0 + ty * 4 + i;
    int b = r / 200, l = r % 200;
#pragma unroll
    for (int j = 0; j < 4; ++j) {
      int n = col0 + tx * 4 + j;
      float v = acc[i][j] + bias[n];
      int h = n >> 6, d = n & 63;
      int bh = b * 4 + h;
      if (z < 4) {
        Qbuf[(((size_t)bh * 4 + z) * 200 + l) * 64 + d] = v;
      } else if (z < 8) {
        int mat = bh * 4 + (z - 4);
        Ktb[(size_t)mat * 12800 + (d >> 2) * 800 + l * 4 + (d & 3)] = v;
      } else {
        Vbuf[((size_t)bh * 200 + l) * 64 + d] = v;
      }
    }
  }
}

// ---------------------------------------------------------------------------
// Kernel 2: KWt[mat][d][n] = sum_m K[mat][m][d] * Wf1[m][n], n padded to 256
// (pad region written as zeros).  KWt stride: mat*16384 + d*256 + n.
// Grid (4 ntiles, 512 mats), 256 thr, k-tile = 64 m.
// ---------------------------------------------------------------------------
__global__ __launch_bounds__(256) void kw_kernel(const float* __restrict__ Wf1,
                                                 const float* __restrict__ Ktb,
                                                 float* __restrict__ KWt) {
  const int mat = blockIdx.y;
  const int n0 = blockIdx.x * 64;

  __shared__ float A_sh[64][68];   // [m][d]
  __shared__ float B_sh[64][64];   // [m][n]

  const int tid = threadIdx.x;
  const int tx = tid & 15, ty = tid >> 4;
  const float4* Ktb4 = (const float4*)(Ktb + (size_t)mat * 12800);

  float acc[4][4] = {};

  for (int m0 = 0; m0 < 256; m0 += 64) {
#pragma unroll
    for (int it = 0; it < 4; ++it) {
      int idx = it * 256 + tid;
      int m = idx >> 4, p = idx & 15;
      float4 kv = make_float4(0.f, 0.f, 0.f, 0.f);
      if (m0 + m < 200) kv = Ktb4[p * 200 + m0 + m];
      *(float4*)&A_sh[m][p * 4] = kv;
    }
#pragma unroll
    for (int it = 0; it < 4; ++it) {
      int idx = it * 256 + tid;
      int m = idx >> 4, nf = idx & 15;
      int gm = m0 + m, gn = n0 + nf * 4;
      float4 wv = make_float4(0.f, 0.f, 0.f, 0.f);
      if (gm < 200 && gn < 200) wv = *(const float4*)&Wf1[gm * 200 + gn];
      *(float4*)&B_sh[m][nf * 4] = wv;
    }
    __syncthreads();
#pragma unroll
    for (int k = 0; k < 64; ++k) {
      float4 av = *(const float4*)&A_sh[k][ty * 4];
      float4 bv = *(const float4*)&B_sh[k][tx * 4];
      acc[0][0] += av.x * bv.x; acc[0][1] += av.x * bv.y; acc[0][2] += av.x * bv.z; acc[0][3] += av.x * bv.w;
      acc[1][0] += av.y * bv.x; acc[1][1] += av.y * bv.y; acc[1][2] += av.y * bv.z; acc[1][3] += av.y * bv.w;
      acc[2][0] += av.z * bv.x; acc[2][1] += av.z * bv.y; acc[2][2] += av.z * bv.z; acc[2][3] += av.z * bv.w;
      acc[3][0] += av.w * bv.x; acc[3][1] += av.w * bv.y; acc[3][2] += av.w * bv.z; acc[3][3] += av.w * bv.w;
    }
    __syncthreads();
  }

#pragma unroll
  for (int i = 0; i < 4; ++i) {
    int d = ty * 4 + i;
    int gn = n0 + tx * 4;
    float4 o = make_float4(acc[i][0], acc[i][1], acc[i][2], acc[i][3]);
    if (gn >= 200) o = make_float4(0.f, 0.f, 0.f, 0.f);   // zero the pad
    *(float4*)&KWt[(size_t)mat * 16384 + (size_t)d * 256 + gn] = o;
  }
}

// ---------------------------------------------------------------------------
// Kernel 3: energy[bh][l][c] = sum_n relu(q[l,cq].KW[ck,n] + bf1[n]) * Wf2[n]
// (bf2 omitted: softmax shift-invariant).
// Grid (13 ltiles, 128 bh), 256 thr. A = 64 rows (16l x 4cq) x 64 d,
// B chunks = 64 d x 128 n (8 chunks cover 4 ck x 256 padded n).
// Per-thread: acc[4][8] + epart[4][4]. No spills.
// ---------------------------------------------------------------------------
__global__ __launch_bounds__(256) void energy_kernel(
    const float* __restrict__ Qbuf, const float* __restrict__ KWt,
    const float* __restrict__ bf1p, const float* __restrict__ Wf2,
    float* __restrict__ Ebuf) {
  const int lt = blockIdx.x, bh = blockIdx.y;
  const int l0 = lt * 16;
  const int tid = threadIdx.x;
  const int tx = tid & 15, ty = tid >> 4;

  __shared__ float A_sh[64][68];    // [row=(l*4+cq)][d]
  __shared__ float B_sh[64][128];   // [d][n-chunk]
  __shared__ float w2_sh[256];
  __shared__ float b1_sh[256];

  w2_sh[tid] = (tid < 200) ? Wf2[tid] : 0.f;
  b1_sh[tid] = (tid < 200) ? bf1p[tid] : 0.f;

  const float4* Q4 = (const float4*)Qbuf;
#pragma unroll
  for (int it = 0; it < 4; ++it) {
    int idx = it * 256 + tid;
    int row = idx >> 4, p = idx & 15;
    int l = row >> 2, cq = row & 3;
    float4 q = make_float4(0.f, 0.f, 0.f, 0.f);
    if (l0 + l < 200) q = Q4[((size_t)(bh * 4 + cq) * 200 + l0 + l) * 16 + p];
    *(float4*)&A_sh[row][p * 4] = q;
  }
  __syncthreads();

  float epart[4][4] = {};   // [cq][ck]

  for (int ch = 0; ch < 8; ++ch) {
    const int ck = ch >> 1;
    const int nb = (ch & 1) * 128;
    const float4* KW4 = (const float4*)(KWt + (size_t)(bh * 4 + ck) * 16384 + nb);
#pragma unroll
    for (int it = 0; it < 8; ++it) {
      int idx = it * 256 + tid;
      int k = idx >> 5, cf = idx & 31;
      *(float4*)&B_sh[k][cf * 4] = KW4[(size_t)k * 64 + cf];
    }
    __syncthreads();

    float acc[4][8] = {};
#pragma unroll
    for (int k = 0; k < 64; ++k) {
      float a0 = A_sh[ty * 4 + 0][k];
      float a1 = A_sh[ty * 4 + 1][k];
      float a2 = A_sh[ty * 4 + 2][k];
      float a3 = A_sh[ty * 4 + 3][k];
      float4 b0 = *(const float4*)&B_sh[k][tx * 4];
      float4 b1 = *(const float4*)&B_sh[k][64 + tx * 4];
      acc[0][0] += a0 * b0.x; acc[0][1] += a0 * b0.y; acc[0][2] += a0 * b0.z; acc[0][3] += a0 * b0.w;
      acc[0][4] += a0 * b1.x; acc[0][5] += a0 * b1.y; acc[0][6] += a0 * b1.z; acc[0][7] += a0 * b1.w;
      acc[1][0] += a1 * b0.x; acc[1][1] += a1 * b0.y; acc[1][2] += a1 * b0.z; acc[1][3] += a1 * b0.w;
      acc[1][4] += a1 * b1.x; acc[1][5] += a1 * b1.y; acc[1][6] += a1 * b1.z; acc[1][7] += a1 * b1.w;
      acc[2][0] += a2 * b0.x; acc[2][1] += a2 * b0.y; acc[2][2] += a2 * b0.z; acc[2][3] += a2 * b0.w;
      acc[2][4] += a2 * b1.x; acc[2][5] += a2 * b1.y; acc[2][6] += a2 * b1.z; acc[2][7] += a2 * b1.w;
      acc[3][0] += a3 * b0.x; acc[3][1] += a3 * b0.y; acc[3][2] += a3 * b0.z; acc[3][3] += a3 * b0.w;
      acc[3][4] += a3 * b1.x; acc[3][5] += a3 * b1.y; acc[3][6] += a3 * b1.z; acc[3][7] += a3 * b1.w;
    }

    // epilogue: relu + Wf2 fold over this n-chunk
#pragma unroll
    for (int i = 0; i < 4; ++i) {
#pragma unroll
      for (int j = 0; j < 8; ++j) {
        int n = nb + ((j < 4) ? (tx * 4 + j) : (64 + tx * 4 + (j - 4)));
        epart[i][ck] += fmaxf(acc[i][j] + b1_sh[n], 0.f) * w2_sh[n];
      }
    }
    __syncthreads();   // before next chunk overwrites B_sh
  }

  // reduce epart over the 16 tx slices via LDS (reuse B_sh)
  float* Ered = &B_sh[0][0];   // [l(=ty)][c][tx] : 16*16*16 floats
#pragma unroll
  for (int cq = 0; cq < 4; ++cq)
#pragma unroll
    for (int ck = 0; ck < 4; ++ck)
      Ered[((ty * 16) + (cq * 4 + ck)) * 16 + tx] = epart[cq][ck];
  __syncthreads();
  {
    int l = tid >> 4, c = tid & 15;
    float e = 0.f;
#pragma unroll
    for (int s = 0; s < 16; ++s) e += Ered[(l * 16 + c) * 16 + s];
    if (l0 + l < 200) Ebuf[((size_t)bh * 200 + l0 + l) * 16 + c] = e;
  }
}

// ---------------------------------------------------------------------------
// Kernel 4: per (bh, 16-l tile): channel softmax -> qw -> attn scores ->
// masked row softmax -> PV -> ctx.
// ---------------------------------------------------------------------------
__global__ __launch_bounds__(256) void attn_kernel(
    const float* __restrict__ Qbuf, const float* __restrict__ Ktb,
    const float* __restrict__ Vbuf, const float* __restrict__ Ebuf,
    const float* __restrict__ mask, float* __restrict__ Ctx) {
  const int lt = blockIdx.x, bh = blockIdx.y;
  const int l0 = lt * 16;
  const int b = bh >> 2, h = bh & 3;
  const int tid = threadIdx.x;

  __shared__ float Qs[16][4][64];      // 16 KB, reused as ctxp in ph6
  __shared__ float qw_sh[4][16][64];   // 16 KB
  __shared__ float att_sh[16][200];    // 12.5 KB
  __shared__ float wght_sh[16][16];
  __shared__ float rinv_sh[16];

  // ph1: channel softmax over 16 c per l
  {
    int l = tid >> 4, c = tid & 15;
    float e = (l0 + l < 200) ? Ebuf[((size_t)bh * 200 + l0 + l) * 16 + c] : 0.f;
    float mx = e;
    mx = fmaxf(mx, __shfl_xor(mx, 8));
    mx = fmaxf(mx, __shfl_xor(mx, 4));
    mx = fmaxf(mx, __shfl_xor(mx, 2));
    mx = fmaxf(mx, __shfl_xor(mx, 1));
    float ex = __expf(e - mx);
    float s = ex;
    s += __shfl_xor(s, 8);
    s += __shfl_xor(s, 4);
    s += __shfl_xor(s, 2);
    s += __shfl_xor(s, 1);
    wght_sh[l][c] = ex / s;
  }
  // ph2: stage Q
  const float4* Q4 = (const float4*)Qbuf;
#pragma unroll
  for (int it = 0; it < 4; ++it) {
    int idx = it * 256 + tid;
    int row = idx >> 4, p = idx & 15;
    int l = row >> 2, cq = row & 3;
    float4 q = make_float4(0.f, 0.f, 0.f, 0.f);
    if (l0 + l < 200) q = Q4[((size_t)(bh * 4 + cq) * 200 + l0 + l) * 16 + p];
    *(float4*)&Qs[l][cq][p * 4] = q;
  }
  __syncthreads();

  // ph3: qw[ck][l][d] = sum_cq w[l][cq*4+ck] * q[l][cq][d]
#pragma unroll
  for (int it = 0; it < 4; ++it) {
    int idx = it * 256 + tid;
    int ck = idx >> 8, l = (idx >> 4) & 15, p = idx & 15;
    float w0 = wght_sh[l][0 * 4 + ck];
    float w1 = wght_sh[l][1 * 4 + ck];
    float w2 = wght_sh[l][2 * 4 + ck];
    float w3 = wght_sh[l][3 * 4 + ck];
    float4 q0 = *(const float4*)&Qs[l][0][p * 4];
    float4 q1 = *(const float4*)&Qs[l][1][p * 4];
    float4 q2 = *(const float4*)&Qs[l][2][p * 4];
    float4 q3 = *(const float4*)&Qs[l][3][p * 4];
    float4 r;
    r.x = w0 * q0.x + w1 * q1.x + w2 * q2.x + w3 * q3.x;
    r.y = w0 * q0.y + w1 * q1.y + w2 * q2.y + w3 * q3.y;
    r.z = w0 * q0.z + w1 * q1.z + w2 * q2.z + w3 * q3.z;
    r.w = w0 * q0.w + w1 * q1.w + w2 * q2.w + w3 * q3.w;
    *(float4*)&qw_sh[ck][l][p * 4] = r;
  }
  __syncthreads();

  // ph4: attn[l][m] = sum_ck qw[l][ck] . K[ck][m]; thread owns m
  {
    const int m = (tid < 200) ? tid : 199;
    float katt[16];
#pragma unroll
    for (int l = 0; l < 16; ++l) katt[l] = 0.f;
#pragma unroll
    for (int ck = 0; ck < 4; ++ck) {
      const float4* K4 = (const float4*)(Ktb + (size_t)(bh * 4 + ck) * 12800);
      float4 kreg[16];
#pragma unroll
      for (int u = 0; u < 16; ++u) kreg[u] = K4[u * 200 + m];
#pragma unroll
      for (int l = 0; l < 16; ++l) {
        float s = 0.f;
#pragma unroll
        for (int u = 0; u < 16; ++u) {
          float4 q = *(const float4*)&qw_sh[ck][l][u * 4];
          s += q.x * kreg[u].x + q.y * kreg[u].y + q.z * kreg[u].z + q.w * kreg[u].w;
        }
        katt[l] += s;
      }
    }
    if (tid < 200) {
#pragma unroll
      for (int l = 0; l < 16; ++l) {
        int gl = l0 + l; if (gl > 199) gl = 199;
        att_sh[l][tid] = katt[l] * SCALE_ + mask[(size_t)gl * 200 + tid];
      }
    }
  }
  __syncthreads();

  // ph5: masked row softmax over m (16 lanes per l)
  {
    int l = tid >> 4, j = tid & 15;
    float mx = -3.0e38f;
    for (int m = j; m < 200; m += 16) mx = fmaxf(mx, att_sh[l][m]);
    mx = fmaxf(mx, __shfl_xor(mx, 8));
    mx = fmaxf(mx, __shfl_xor(mx, 4));
    mx = fmaxf(mx, __shfl_xor(mx, 2));
    mx = fmaxf(mx, __shfl_xor(mx, 1));
    float sum = 0.f;
    for (int m = j; m < 200; m += 16) {
      float ex = __expf(att_sh[l][m] - mx);
      att_sh[l][m] = ex;
      sum += ex;
    }
    sum += __shfl_xor(sum, 8);
    sum += __shfl_xor(sum, 4);
    sum += __shfl_xor(sum, 2);
    sum += __shfl_xor(sum, 1);
    if (j == 0) rinv_sh[l] = 1.f / sum;
  }
  __syncthreads();

  // ph6: PV partials. thread (d, mg) over 50 m, 16 l.
  {
    int d = tid & 63, mg = tid >> 6;
    float acc[16];
#pragma unroll
    for (int l = 0; l < 16; ++l) acc[l] = 0.f;
    const float* Vb = Vbuf + (size_t)bh * 200 * 64;
    for (int m = mg * 50; m < mg * 50 + 50; ++m) {
      float v = Vb[m * 64 + d];
#pragma unroll
      for (int l = 0; l < 16; ++l) acc[l] += att_sh[l][m] * v;
    }
    float* ctxp = &Qs[0][0][0];   // Qs dead since ph3 (sync'd since)
#pragma unroll
    for (int l = 0; l < 16; ++l) ctxp[(mg * 16 + l) * 64 + d] = acc[l];
  }
  __syncthreads();

  // ph7: combine partials, normalize, write ctx
  {
    const float* ctxp = &Qs[0][0][0];
#pragma unroll
    for (int it = 0; it < 4; ++it) {
      int idx = it * 256 + tid;
      int l = idx >> 6, d = idx & 63;
      float c = (ctxp[(0 * 16 + l) * 64 + d] + ctxp[(1 * 16 + l) * 64 + d] +
                 ctxp[(2 * 16 + l) * 64 + d] + ctxp[(3 * 16 + l) * 64 + d]) * rinv_sh[l];
      if (l0 + l < 200)
        Ctx[((size_t)b * 200 + l0 + l) * 256 + h * 64 + d] = c;
    }
  }
}

// ---------------------------------------------------------------------------
// Kernel 5: x = ctx @ Wd + bd + input; LayerNorm(x). One block per row.
// ---------------------------------------------------------------------------
__global__ __launch_bounds__(256) void out_ln_kernel(
    const float* __restrict__ Ctx, const float* __restrict__ Wd,
    const float* __restrict__ bd, const float* __restrict__ input,
    const float* __restrict__ gamma, const float* __restrict__ beta,
    float* __restrict__ out) {
  const int row = blockIdx.x;
  const int n = threadIdx.x;
  __shared__ float c_sh[256];
  __shared__ float red[4];

  c_sh[n] = Ctx[(size_t)row * 256 + n];
  __syncthreads();

  float acc = bd[n];
#pragma unroll 8
  for (int k = 0; k < 256; ++k) acc += c_sh[k] * Wd[k * 256 + n];
  float x = acc + input[(size_t)row * 256 + n];

  float s = x;
#pragma unroll
  for (int o = 32; o; o >>= 1) s += __shfl_xor(s, o);
  if ((n & 63) == 0) red[n >> 6] = s;
  __syncthreads();
  float mu = (red[0] + red[1] + red[2] + red[3]) * (1.f / 256.f);
  __syncthreads();
  float dv = (x - mu) * (x - mu);
#pragma unroll
  for (int o = 32; o; o >>= 1) dv += __shfl_xor(dv, o);
  if ((n & 63) == 0) red[n >> 6] = dv;
  __syncthreads();
  float var = (red[0] + red[1] + red[2] + red[3]) * (1.f / 256.f);

  out[(size_t)row * 256 + n] = (x - mu) * rsqrtf(var + EPS_) * gamma[n] + beta[n];
}

// ---------------------------------------------------------------------------
extern "C" void kernel_launch(void* const* d_in, const int* in_sizes, int n_in,
                              void* d_out, int out_size, void* d_ws, size_t ws_size,
                              hipStream_t stream) {
  const float* input = (const float*)d_in[0];
  const float* attrt = (const float*)d_in[1];   // (F,B,L,1,H)
  const float* pos   = (const float*)d_in[2];
  const float* mask  = (const float*)d_in[3];
  const float* Wq  = (const float*)d_in[4];   const float* bq  = (const float*)d_in[5];
  const float* Wk  = (const float*)d_in[6];   const float* bk  = (const float*)d_in[7];
  const float* Wv  = (const float*)d_in[8];   const float* bv  = (const float*)d_in[9];
  const float* Wqp = (const float*)d_in[10];  const float* bqp = (const float*)d_in[11];
  const float* Wkp = (const float*)d_in[12];  const float* bkp = (const float*)d_in[13];
  const float* Wq_a = (const float*)d_in[16]; const float* bq_a = (const float*)d_in[17];
  const float* Wk_a = (const float*)d_in[18]; const float* bk_a = (const float*)d_in[19];
  const float* Wf1 = (const float*)d_in[22];  const float* bf1 = (const float*)d_in[23];
  const float* Wf2 = (const float*)d_in[24];
  const float* Wd  = (const float*)d_in[26];  const float* bd  = (const float*)d_in[27];
  const float* gamma = (const float*)d_in[28]; const float* beta = (const float*)d_in[29];

  const float* attr0 = attrt;
  const float* attr1 = attrt + (size_t)B_ * L_ * H_;

  float* ws = (float*)d_ws;
  float* Qbuf = ws;                     // 6,553,600 floats
  float* Ktb  = Qbuf + 6553600;         // 6,553,600
  float* KWt  = Ktb + 6553600;          // 8,388,608 (512 mats x 64 d x 256 n-pad)
  float* Vbuf = KWt + 8388608;          // 1,638,400
  float* Ebuf = Vbuf + 1638400;         // 409,600
  float* Ctx  = KWt;                    // alias: KWt dead after energy_kernel

  ProjArgs pa;
  // Q channels: 0=q_i, 1=q_p, 2=q_a0, 3=q_a1
  pa.X[0] = input; pa.W[0] = Wq;              pa.Bi[0] = bq;
  pa.X[1] = pos;   pa.W[1] = Wqp;             pa.Bi[1] = bqp;
  pa.X[2] = attr0; pa.W[2] = Wq_a;            pa.Bi[2] = bq_a;
  pa.X[3] = attr1; pa.W[3] = Wq_a + 65536;    pa.Bi[3] = bq_a + 256;
  // K channels: 0=k_i, 1=k_a0, 2=k_a1, 3=k_p
  pa.X[4] = input; pa.W[4] = Wk;              pa.Bi[4] = bk;
  pa.X[5] = attr0; pa.W[5] = Wk_a;            pa.Bi[5] = bk_a;
  pa.X[6] = attr1; pa.W[6] = Wk_a + 65536;    pa.Bi[6] = bk_a + 256;
  pa.X[7] = pos;   pa.W[7] = Wkp;             pa.Bi[7] = bkp;
  // V
  pa.X[8] = input; pa.W[8] = Wv;              pa.Bi[8] = bv;

  proj_kernel<<<dim3(4, 100, 9), dim3(256), 0, stream>>>(pa, Qbuf, Ktb, Vbuf);
  kw_kernel<<<dim3(4, 512), dim3(256), 0, stream>>>(Wf1, Ktb, KWt);
  energy_kernel<<<dim3(13, 128), dim3(256), 0, stream>>>(Qbuf, KWt, bf1, Wf2, Ebuf);
  attn_kernel<<<dim3(13, 128), dim3(256), 0, stream>>>(Qbuf, Ktb, Vbuf, Ebuf, mask, Ctx);
  out_ln_kernel<<<dim3(6400), dim3(256), 0, stream>>>(Ctx, Wd, bd, input,
                                                      gamma, beta, (float*)d_out);
}

// Round 4
// 408.470 us; speedup vs baseline: 16.5687x; 2.0944x over previous
//
#include <hip/hip_runtime.h>
#include <hip/hip_bf16.h>

// Problem constants
#define B_    32
#define L_    200
#define H_    256
#define NH_   4
#define D_    64
#define SCALE_ 0.125f
#define EPS_  1e-12f

typedef unsigned short u16;
typedef __attribute__((ext_vector_type(8))) short bf16x8;
typedef __attribute__((ext_vector_type(4))) float f32x4;

__device__ __forceinline__ float b2f(u16 u) {
  union { unsigned int i; float f; } v; v.i = ((unsigned int)u) << 16; return v.f;
}
__device__ __forceinline__ u16 f2b(float f) {
  union { float f; unsigned int i; } v; v.f = f;
  unsigned int u = v.i;
  return (u16)((u + 0x7FFF + ((u >> 16) & 1)) >> 16);   // RNE
}

struct ProjArgs {
  const float* X[9];
  const float* W[9];
  const float* Bi[9];
};

// ---------------------------------------------------------------------------
// Kernel 1: 9 projections  out = X @ W + bias.
// Q -> Qbuf f32 [bh][cq][l][64]
// K -> Kb bf16 [mat][208 l][64 d]   (mat = bh*4+ck; rows 200..207 unwritten)
// V -> Vt bf16 [bh][64 d][224 m]    (cols 200..223 unwritten)
// ---------------------------------------------------------------------------
__global__ __launch_bounds__(256) void proj_kernel(ProjArgs pa,
                                                   float* __restrict__ Qbuf,
                                                   u16* __restrict__ Kb,
                                                   u16* __restrict__ Vt) {
  const int z = blockIdx.z;
  const float* __restrict__ X    = pa.X[z];
  const float* __restrict__ W    = pa.W[z];
  const float* __restrict__ bias = pa.Bi[z];

  __shared__ float As[16][65];
  __shared__ float Bs[16][64];

  const int tid = threadIdx.x;
  const int tx = tid & 15, ty = tid >> 4;
  const int row0 = blockIdx.y * 64, col0 = blockIdx.x * 64;

  float acc[4][4] = {};

  for (int k0 = 0; k0 < 256; k0 += 16) {
    for (int i = tid; i < 1024; i += 256) {
      int m = i >> 4, k = i & 15;
      As[k][m] = X[(row0 + m) * 256 + k0 + k];
    }
    for (int i = tid; i < 1024; i += 256) {
      int k = i >> 6, n = i & 63;
      Bs[k][n] = W[(k0 + k) * 256 + col0 + n];
    }
    __syncthreads();
#pragma unroll
    for (int k = 0; k < 16; ++k) {
      float a0 = As[k][ty * 4 + 0];
      float a1 = As[k][ty * 4 + 1];
      float a2 = As[k][ty * 4 + 2];
      float a3 = As[k][ty * 4 + 3];
      float4 bv = *(const float4*)&Bs[k][tx * 4];
      acc[0][0] += a0 * bv.x; acc[0][1] += a0 * bv.y; acc[0][2] += a0 * bv.z; acc[0][3] += a0 * bv.w;
      acc[1][0] += a1 * bv.x; acc[1][1] += a1 * bv.y; acc[1][2] += a1 * bv.z; acc[1][3] += a1 * bv.w;
      acc[2][0] += a2 * bv.x; acc[2][1] += a2 * bv.y; acc[2][2] += a2 * bv.z; acc[2][3] += a2 * bv.w;
      acc[3][0] += a3 * bv.x; acc[3][1] += a3 * bv.y; acc[3][2] += a3 * bv.z; acc[3][3] += a3 * bv.w;
    }
    __syncthreads();
  }

#pragma unroll
  for (int i = 0; i < 4; ++i) {
    int r = row0 + ty * 4 + i;
    int b = r / 200, l = r % 200;
#pragma unroll
    for (int j = 0; j < 4; ++j) {
      int n = col0 + tx * 4 + j;
      float v = acc[i][j] + bias[n];
      int h = n >> 6, d = n & 63;
      int bh = b * 4 + h;
      if (z < 4) {
        Qbuf[(((size_t)bh * 4 + z) * 200 + l) * 64 + d] = v;
      } else if (z < 8) {
        int mat = bh * 4 + (z - 4);
        Kb[((size_t)mat * 208 + l) * 64 + d] = f2b(v);
      } else {
        Vt[((size_t)bh * 64 + d) * 224 + l] = f2b(v);
      }
    }
  }
}

// ---------------------------------------------------------------------------
// Kernel 2: KWb[mat][n][d] = sum_m Wf1[m][n] * K[mat][m][d], bf16 out,
// n padded to 256 (pad rows = 0 since A is zero-filled).  f32 compute.
// Grid (4 ntiles, 512 mats), 256 thr, k-tile = 64 m.
// ---------------------------------------------------------------------------
__global__ __launch_bounds__(256) void kw_kernel(const float* __restrict__ Wf1,
                                                 const u16* __restrict__ Kb,
                                                 u16* __restrict__ KWb) {
  const int mat = blockIdx.y;
  const int n0 = blockIdx.x * 64;

  __shared__ float A_sh[64][68];   // [m][n]
  __shared__ float B_sh[64][64];   // [m][d]

  const int tid = threadIdx.x;
  const int tx = tid & 15, ty = tid >> 4;

  float acc[4][4] = {};

  for (int m0 = 0; m0 < 256; m0 += 64) {
    for (int idx = tid; idx < 4096; idx += 256) {
      int m = idx >> 6, n = idx & 63;
      int gm = m0 + m, gn = n0 + n;
      A_sh[m][n] = (gm < 200 && gn < 200) ? Wf1[gm * 200 + gn] : 0.f;
    }
    for (int idx = tid; idx < 4096; idx += 256) {
      int m = idx >> 6, d = idx & 63;
      int gm = m0 + m;
      B_sh[m][d] = (gm < 200) ? b2f(Kb[((size_t)mat * 208 + gm) * 64 + d]) : 0.f;
    }
    __syncthreads();
#pragma unroll
    for (int k = 0; k < 64; ++k) {
      float a0 = A_sh[k][ty * 4 + 0];
      float a1 = A_sh[k][ty * 4 + 1];
      float a2 = A_sh[k][ty * 4 + 2];
      float a3 = A_sh[k][ty * 4 + 3];
      float4 bv = *(const float4*)&B_sh[k][tx * 4];
      acc[0][0] += a0 * bv.x; acc[0][1] += a0 * bv.y; acc[0][2] += a0 * bv.z; acc[0][3] += a0 * bv.w;
      acc[1][0] += a1 * bv.x; acc[1][1] += a1 * bv.y; acc[1][2] += a1 * bv.z; acc[1][3] += a1 * bv.w;
      acc[2][0] += a2 * bv.x; acc[2][1] += a2 * bv.y; acc[2][2] += a2 * bv.z; acc[2][3] += a2 * bv.w;
      acc[3][0] += a3 * bv.x; acc[3][1] += a3 * bv.y; acc[3][2] += a3 * bv.z; acc[3][3] += a3 * bv.w;
    }
    __syncthreads();
  }

#pragma unroll
  for (int i = 0; i < 4; ++i) {
    int n = n0 + ty * 4 + i;
    unsigned int p0 = f2b(acc[i][0]) | ((unsigned int)f2b(acc[i][1]) << 16);
    unsigned int p1 = f2b(acc[i][2]) | ((unsigned int)f2b(acc[i][3]) << 16);
    u16* dst = &KWb[((size_t)mat * 256 + n) * 64 + tx * 4];
    *(unsigned int*)(dst)     = p0;
    *(unsigned int*)(dst + 2) = p1;
  }
}

// ---------------------------------------------------------------------------
// Kernel 3: fused MFMA kernel per (bh, 32-l tile):
// energy (Q.KW relu.Wf2) -> channel softmax -> qw -> scores (qw.K) ->
// row softmax -> PV -> ctx.
// MFMA 16x16x32 bf16. A: row=lane&15, k=(lane>>4)*8+j. C/D: col=lane&15,
// row=(lane>>4)*4+j.
// ---------------------------------------------------------------------------
__global__ __launch_bounds__(256) void fused_kernel(
    const float* __restrict__ Qbuf, const u16* __restrict__ Kb,
    const u16* __restrict__ KWb, const u16* __restrict__ Vt,
    const float* __restrict__ mask, const float* __restrict__ bf1,
    const float* __restrict__ Wf2, float* __restrict__ Ctx) {
  const int lt = blockIdx.x, bh = blockIdx.y;
  const int l0 = lt * 32;
  const int b = bh >> 2, h = bh & 3;
  const int tid = threadIdx.x;
  const int wv = tid >> 6, ln = tid & 63;
  const int lrow = ln & 15, lk8 = ln >> 4;

  __shared__ u16  QbfPb[9216];       // Qbf[128 rows][72] ; later pb[32][232]
  __shared__ u16  qwl[32 * 264];     // qw bf16 [32 l][264] (k = ck*64+d)
  __shared__ float att[32 * 208];    // scores f32
  __shared__ float El[512];          // energy [32 l][16 c]
  __shared__ float wg[512];          // channel weights
  __shared__ float b1s[256], w2s[256];

  b1s[tid] = (tid < 200) ? bf1[tid] : 0.f;
  w2s[tid] = (tid < 200) ? Wf2[tid] : 0.f;

  // ---- stage Qbf bf16: row r = cq*32+l, cols d 0..63, row pitch 72
  {
    int row = tid >> 1, hf = tid & 1;
    int cq = row >> 5, lq = row & 31;
    int gl = l0 + lq;
    const float4* src = (const float4*)&Qbuf[(((size_t)bh * 4 + cq) * 200 + (gl < 200 ? gl : 0)) * 64 + hf * 32];
#pragma unroll
    for (int i = 0; i < 8; ++i) {
      float4 v = (gl < 200) ? src[i] : make_float4(0.f, 0.f, 0.f, 0.f);
      unsigned int p0 = f2b(v.x) | ((unsigned int)f2b(v.y) << 16);
      unsigned int p1 = f2b(v.z) | ((unsigned int)f2b(v.w) << 16);
      *(unsigned int*)&QbfPb[row * 72 + hf * 32 + i * 4]     = p0;
      *(unsigned int*)&QbfPb[row * 72 + hf * 32 + i * 4 + 2] = p1;
    }
  }
  __syncthreads();

  // ---- phase E: energy via MFMA.  wave owns M-tiles 2wv, 2wv+1 (32 rows).
  {
    bf16x8 aE[2][2];
#pragma unroll
    for (int mt = 0; mt < 2; ++mt)
#pragma unroll
      for (int ks = 0; ks < 2; ++ks)
        aE[mt][ks] = *(const bf16x8*)&QbfPb[((wv * 2 + mt) * 16 + lrow) * 72 + ks * 32 + lk8 * 8];

    float eacc[2][4][4];
#pragma unroll
    for (int mt = 0; mt < 2; ++mt)
#pragma unroll
      for (int ck = 0; ck < 4; ++ck)
#pragma unroll
        for (int j = 0; j < 4; ++j) eacc[mt][ck][j] = 0.f;

#pragma unroll
    for (int ck = 0; ck < 4; ++ck) {
      const u16* KWm = KWb + (size_t)(bh * 4 + ck) * 16384;
#pragma unroll 4
      for (int nt = 0; nt < 16; ++nt) {
        bf16x8 b0 = *(const bf16x8*)&KWm[(nt * 16 + lrow) * 64 + lk8 * 8];
        bf16x8 b1 = *(const bf16x8*)&KWm[(nt * 16 + lrow) * 64 + 32 + lk8 * 8];
        f32x4 c0 = {0.f, 0.f, 0.f, 0.f}, c1 = {0.f, 0.f, 0.f, 0.f};
        c0 = __builtin_amdgcn_mfma_f32_16x16x32_bf16(aE[0][0], b0, c0, 0, 0, 0);
        c0 = __builtin_amdgcn_mfma_f32_16x16x32_bf16(aE[0][1], b1, c0, 0, 0, 0);
        c1 = __builtin_amdgcn_mfma_f32_16x16x32_bf16(aE[1][0], b0, c1, 0, 0, 0);
        c1 = __builtin_amdgcn_mfma_f32_16x16x32_bf16(aE[1][1], b1, c1, 0, 0, 0);
        float b1n = b1s[nt * 16 + lrow];
        float w2n = w2s[nt * 16 + lrow];
#pragma unroll
        for (int j = 0; j < 4; ++j) {
          eacc[0][ck][j] += fmaxf(c0[j] + b1n, 0.f) * w2n;
          eacc[1][ck][j] += fmaxf(c1[j] + b1n, 0.f) * w2n;
        }
      }
    }

    // reduce over the 16 col-lanes; lane&15==0 writes E[l][c]
#pragma unroll
    for (int mt = 0; mt < 2; ++mt)
#pragma unroll
      for (int ck = 0; ck < 4; ++ck)
#pragma unroll
        for (int j = 0; j < 4; ++j) {
          float v = eacc[mt][ck][j];
          v += __shfl_xor(v, 1);
          v += __shfl_xor(v, 2);
          v += __shfl_xor(v, 4);
          v += __shfl_xor(v, 8);
          if (lrow == 0) {
            int r = (wv * 2 + mt) * 16 + lk8 * 4 + j;   // r = cq*32 + l
            El[(r & 31) * 16 + (r >> 5) * 4 + ck] = v;
          }
        }
  }
  __syncthreads();

  // ---- channel softmax over 16 c per l
#pragma unroll
  for (int it = 0; it < 2; ++it) {
    int l = it * 16 + (tid >> 4), c = tid & 15;
    float e = El[l * 16 + c];
    float mx = e;
    mx = fmaxf(mx, __shfl_xor(mx, 8));
    mx = fmaxf(mx, __shfl_xor(mx, 4));
    mx = fmaxf(mx, __shfl_xor(mx, 2));
    mx = fmaxf(mx, __shfl_xor(mx, 1));
    float ex = __expf(e - mx);
    float s = ex;
    s += __shfl_xor(s, 8);
    s += __shfl_xor(s, 4);
    s += __shfl_xor(s, 2);
    s += __shfl_xor(s, 1);
    wg[l * 16 + c] = ex / s;
  }
  __syncthreads();

  // ---- qw[l][ck*64+d] = sum_cq w[l][cq*4+ck] * q[cq][l][d]   (bf16 out)
  {
    int lq = tid >> 3, d0 = (tid & 7) * 8;
    float qf[4][8];
#pragma unroll
    for (int cq = 0; cq < 4; ++cq) {
      bf16x8 q8 = *(const bf16x8*)&QbfPb[(cq * 32 + lq) * 72 + d0];
#pragma unroll
      for (int j = 0; j < 8; ++j) qf[cq][j] = b2f((u16)q8[j]);
    }
    float wv_[16];
#pragma unroll
    for (int c = 0; c < 16; ++c) wv_[c] = wg[lq * 16 + c];
#pragma unroll
    for (int ck = 0; ck < 4; ++ck) {
      float a[8];
#pragma unroll
      for (int j = 0; j < 8; ++j)
        a[j] = wv_[0 * 4 + ck] * qf[0][j] + wv_[1 * 4 + ck] * qf[1][j] +
               wv_[2 * 4 + ck] * qf[2][j] + wv_[3 * 4 + ck] * qf[3][j];
#pragma unroll
      for (int p = 0; p < 4; ++p) {
        unsigned int pk = f2b(a[2 * p]) | ((unsigned int)f2b(a[2 * p + 1]) << 16);
        *(unsigned int*)&qwl[lq * 264 + ck * 64 + d0 + 2 * p] = pk;
      }
    }
  }
  __syncthreads();

  // ---- scores: wave handles m-tiles wv, wv+4, wv+8, (wv+12)
  for (int mt = wv; mt < 13; mt += 4) {
    f32x4 sc0 = {0.f, 0.f, 0.f, 0.f}, sc1 = {0.f, 0.f, 0.f, 0.f};
#pragma unroll
    for (int ks = 0; ks < 8; ++ks) {
      int ck = ks >> 1, dd = (ks & 1) * 32 + lk8 * 8;
      const u16* Km = Kb + (size_t)(bh * 4 + ck) * 208 * 64;
      bf16x8 bK = *(const bf16x8*)&Km[(mt * 16 + lrow) * 64 + dd];
      bf16x8 a0 = *(const bf16x8*)&qwl[lrow * 264 + ck * 64 + dd];
      bf16x8 a1 = *(const bf16x8*)&qwl[(16 + lrow) * 264 + ck * 64 + dd];
      sc0 = __builtin_amdgcn_mfma_f32_16x16x32_bf16(a0, bK, sc0, 0, 0, 0);
      sc1 = __builtin_amdgcn_mfma_f32_16x16x32_bf16(a1, bK, sc1, 0, 0, 0);
    }
    int m = mt * 16 + lrow;
    int gm = (m > 199) ? 199 : m;
#pragma unroll
    for (int j = 0; j < 4; ++j) {
      int la = lk8 * 4 + j;
      int gla = l0 + la; if (gla > 199) gla = 199;
      int lb = 16 + lk8 * 4 + j;
      int glb = l0 + lb; if (glb > 199) glb = 199;
      att[la * 208 + m] = sc0[j] * SCALE_ + mask[(size_t)gla * 200 + gm];
      att[lb * 208 + m] = sc1[j] * SCALE_ + mask[(size_t)glb * 200 + gm];
    }
  }
  __syncthreads();

  // ---- row softmax over m (exclude m>=200), write pb bf16 [32][232]
#pragma unroll
  for (int it = 0; it < 2; ++it) {
    int l = it * 16 + (tid >> 4), j = tid & 15;
    float mx = -3.0e38f;
    for (int m = j; m < 200; m += 16) mx = fmaxf(mx, att[l * 208 + m]);
    mx = fmaxf(mx, __shfl_xor(mx, 8));
    mx = fmaxf(mx, __shfl_xor(mx, 4));
    mx = fmaxf(mx, __shfl_xor(mx, 2));
    mx = fmaxf(mx, __shfl_xor(mx, 1));
    float s = 0.f;
    for (int m = j; m < 200; m += 16) {
      float ex = __expf(att[l * 208 + m] - mx);
      att[l * 208 + m] = ex;
      s += ex;
    }
    s += __shfl_xor(s, 8);
    s += __shfl_xor(s, 4);
    s += __shfl_xor(s, 2);
    s += __shfl_xor(s, 1);
    float rinv = 1.f / s;
    u16* pb = QbfPb;
    for (int m = j; m < 200; m += 16) pb[l * 232 + m] = f2b(att[l * 208 + m] * rinv);
    for (int m = 200 + j; m < 232; m += 16) pb[l * 232 + m] = 0;
  }
  __syncthreads();

  // ---- PV: wave owns d-tile wv (16 d).  K = 224 (7 steps), pad probs = 0.
  {
    const u16* Vb = Vt + (size_t)bh * 64 * 224;
    f32x4 pc0 = {0.f, 0.f, 0.f, 0.f}, pc1 = {0.f, 0.f, 0.f, 0.f};
#pragma unroll
    for (int ks = 0; ks < 7; ++ks) {
      int mm = ks * 32 + lk8 * 8;
      bf16x8 a0 = *(const bf16x8*)&QbfPb[lrow * 232 + mm];
      bf16x8 a1 = *(const bf16x8*)&QbfPb[(16 + lrow) * 232 + mm];
      bf16x8 bV = *(const bf16x8*)&Vb[(wv * 16 + lrow) * 224 + mm];
      pc0 = __builtin_amdgcn_mfma_f32_16x16x32_bf16(a0, bV, pc0, 0, 0, 0);
      pc1 = __builtin_amdgcn_mfma_f32_16x16x32_bf16(a1, bV, pc1, 0, 0, 0);
    }
#pragma unroll
    for (int j = 0; j < 4; ++j) {
      int la = lk8 * 4 + j, lb = 16 + lk8 * 4 + j;
      int gla = l0 + la, glb = l0 + lb;
      int d = h * 64 + wv * 16 + lrow;
      if (gla < 200) Ctx[((size_t)b * 200 + gla) * 256 + d] = pc0[j];
      if (glb < 200) Ctx[((size_t)b * 200 + glb) * 256 + d] = pc1[j];
    }
  }
}

// ---------------------------------------------------------------------------
// Kernel 4: x = ctx @ Wd + bd + input; LayerNorm(x). 16 rows per block.
// ---------------------------------------------------------------------------
__global__ __launch_bounds__(256) void out_ln_kernel(
    const float* __restrict__ Ctx, const float* __restrict__ Wd,
    const float* __restrict__ bd, const float* __restrict__ input,
    const float* __restrict__ gamma, const float* __restrict__ beta,
    float* __restrict__ out) {
  const int r0 = blockIdx.x * 16;
  const int n = threadIdx.x;
  const int wvv = n >> 6;
  __shared__ float c_sh[16][256];
  __shared__ float redA[16][4];
  __shared__ float redB[16][4];

#pragma unroll
  for (int it = 0; it < 4; ++it) {
    int idx = it * 256 + n;
    int r = idx >> 6, q4 = (idx & 63) * 4;
    *(float4*)&c_sh[r][q4] = *(const float4*)&Ctx[((size_t)r0 + r) * 256 + q4];
  }
  __syncthreads();

  float acc[16];
#pragma unroll
  for (int r = 0; r < 16; ++r) acc[r] = 0.f;

  for (int k0 = 0; k0 < 256; k0 += 4) {
    float w0 = Wd[(k0 + 0) * 256 + n];
    float w1 = Wd[(k0 + 1) * 256 + n];
    float w2 = Wd[(k0 + 2) * 256 + n];
    float w3 = Wd[(k0 + 3) * 256 + n];
#pragma unroll
    for (int r = 0; r < 16; ++r) {
      float4 cv = *(const float4*)&c_sh[r][k0];
      acc[r] += cv.x * w0 + cv.y * w1 + cv.z * w2 + cv.w * w3;
    }
  }

  float bdn = bd[n];
#pragma unroll
  for (int r = 0; r < 16; ++r) {
    float x = acc[r] + bdn + input[((size_t)r0 + r) * 256 + n];
    acc[r] = x;
    float s = x;
#pragma unroll
    for (int o = 32; o; o >>= 1) s += __shfl_xor(s, o);
    if ((n & 63) == 0) redA[r][wvv] = s;
  }
  __syncthreads();
#pragma unroll
  for (int r = 0; r < 16; ++r) {
    float mu = (redA[r][0] + redA[r][1] + redA[r][2] + redA[r][3]) * (1.f / 256.f);
    float dv = (acc[r] - mu) * (acc[r] - mu);
#pragma unroll
    for (int o = 32; o; o >>= 1) dv += __shfl_xor(dv, o);
    if ((n & 63) == 0) redB[r][wvv] = dv;
  }
  __syncthreads();
  float gn = gamma[n], bn = beta[n];
#pragma unroll
  for (int r = 0; r < 16; ++r) {
    float mu = (redA[r][0] + redA[r][1] + redA[r][2] + redA[r][3]) * (1.f / 256.f);
    float var = (redB[r][0] + redB[r][1] + redB[r][2] + redB[r][3]) * (1.f / 256.f);
    out[((size_t)r0 + r) * 256 + n] = (acc[r] - mu) * rsqrtf(var + EPS_) * gn + bn;
  }
}

// ---------------------------------------------------------------------------
extern "C" void kernel_launch(void* const* d_in, const int* in_sizes, int n_in,
                              void* d_out, int out_size, void* d_ws, size_t ws_size,
                              hipStream_t stream) {
  const float* input = (const float*)d_in[0];
  const float* attrt = (const float*)d_in[1];   // (F,B,L,1,H)
  const float* pos   = (const float*)d_in[2];
  const float* mask  = (const float*)d_in[3];
  const float* Wq  = (const float*)d_in[4];   const float* bq  = (const float*)d_in[5];
  const float* Wk  = (const float*)d_in[6];   const float* bk  = (const float*)d_in[7];
  const float* Wv  = (const float*)d_in[8];   const float* bv  = (const float*)d_in[9];
  const float* Wqp = (const float*)d_in[10];  const float* bqp = (const float*)d_in[11];
  const float* Wkp = (const float*)d_in[12];  const float* bkp = (const float*)d_in[13];
  const float* Wq_a = (const float*)d_in[16]; const float* bq_a = (const float*)d_in[17];
  const float* Wk_a = (const float*)d_in[18]; const float* bk_a = (const float*)d_in[19];
  const float* Wf1 = (const float*)d_in[22];  const float* bf1 = (const float*)d_in[23];
  const float* Wf2 = (const float*)d_in[24];
  const float* Wd  = (const float*)d_in[26];  const float* bd  = (const float*)d_in[27];
  const float* gamma = (const float*)d_in[28]; const float* beta = (const float*)d_in[29];

  const float* attr0 = attrt;
  const float* attr1 = attrt + (size_t)B_ * L_ * H_;

  float* ws = (float*)d_ws;
  float* Qbuf = ws;                                   // 6,553,600 f32
  u16*   Kb   = (u16*)(ws + 6553600);                 // 512*208*64 u16 = 3,407,872 slots
  u16*   Vt   = (u16*)(ws + 6553600 + 3407872);       // 128*64*224 u16 = 917,504 slots
  u16*   KWb  = (u16*)(ws + 6553600 + 3407872 + 917504);   // 512*256*64 u16 = 4,194,304 slots
  float* Ctx  = ws + 6553600 + 3407872 + 917504 + 4194304; // 1,638,400 f32

  ProjArgs pa;
  // Q channels: 0=q_i, 1=q_p, 2=q_a0, 3=q_a1
  pa.X[0] = input; pa.W[0] = Wq;              pa.Bi[0] = bq;
  pa.X[1] = pos;   pa.W[1] = Wqp;             pa.Bi[1] = bqp;
  pa.X[2] = attr0; pa.W[2] = Wq_a;            pa.Bi[2] = bq_a;
  pa.X[3] = attr1; pa.W[3] = Wq_a + 65536;    pa.Bi[3] = bq_a + 256;
  // K channels: 0=k_i, 1=k_a0, 2=k_a1, 3=k_p
  pa.X[4] = input; pa.W[4] = Wk;              pa.Bi[4] = bk;
  pa.X[5] = attr0; pa.W[5] = Wk_a;            pa.Bi[5] = bk_a;
  pa.X[6] = attr1; pa.W[6] = Wk_a + 65536;    pa.Bi[6] = bk_a + 256;
  pa.X[7] = pos;   pa.W[7] = Wkp;             pa.Bi[7] = bkp;
  // V
  pa.X[8] = input; pa.W[8] = Wv;              pa.Bi[8] = bv;

  proj_kernel<<<dim3(4, 100, 9), dim3(256), 0, stream>>>(pa, Qbuf, Kb, Vt);
  kw_kernel<<<dim3(4, 512), dim3(256), 0, stream>>>(Wf1, Kb, KWb);
  fused_kernel<<<dim3(7, 128), dim3(256), 0, stream>>>(Qbuf, Kb, KWb, Vt,
                                                       mask, bf1, Wf2, Ctx);
  out_ln_kernel<<<dim3(400), dim3(256), 0, stream>>>(Ctx, Wd, bd, input,
                                                     gamma, beta, (float*)d_out);
}

// Round 5
// 188.175 us; speedup vs baseline: 35.9654x; 2.1707x over previous
//
#include <hip/hip_runtime.h>
#include <hip/hip_bf16.h>

// Problem constants
#define B_    32
#define L_    200
#define H_    256
#define NH_   4
#define D_    64
#define SCALE_ 0.125f
#define EPS_  1e-12f

typedef unsigned short u16;
typedef __attribute__((ext_vector_type(8))) short bf16x8;
typedef __attribute__((ext_vector_type(4))) float f32x4;

__device__ __forceinline__ float b2f(u16 u) {
  union { unsigned int i; float f; } v; v.i = ((unsigned int)u) << 16; return v.f;
}
__device__ __forceinline__ u16 f2b(float f) {
  union { float f; unsigned int i; } v; v.f = f;
  unsigned int u = v.i;
  return (u16)((u + 0x7FFF + ((u >> 16) & 1)) >> 16);   // RNE
}

struct PrepArgs {
  const float* X[4];     // input, pos, attr0, attr1
  const float* W[10];    // Wq,Wqp,Wqa0,Wqa1, Wk,Wka0,Wka1,Wkp, Wv, Wd
  const float* Wf1;
};
struct BiasArgs { const float* Bi[9]; };

// ---------------------------------------------------------------------------
// Kernel 0: prep — bf16 conversions, weight transposes, pad zero-fills.
// Xb[4][6400][256], Wb[10][n=256][k=256] (=W^T), Wf1T[208][224] (zero-padded),
// Qb pad rows 200..223 = 0, Kb pad rows 200..207 = 0.
// ---------------------------------------------------------------------------
__global__ __launch_bounds__(256) void prep_kernel(PrepArgs pa,
    u16* __restrict__ Xb, u16* __restrict__ Wb, u16* __restrict__ Wf1T,
    u16* __restrict__ Qb, u16* __restrict__ Kb) {
  const int N0 = 6553600, N1 = 655360, N2 = 46592, N3 = 786432, N4 = 262144;
  const int total = N0 + N1 + N2 + N3 + N4;
  for (int idx = blockIdx.x * 256 + threadIdx.x; idx < total;
       idx += gridDim.x * 256) {
    if (idx < N0) {
      int i = idx;
      int s = i / 1638400, r = i % 1638400;
      Xb[i] = f2b(pa.X[s][r]);
    } else if (idx < N0 + N1) {
      int i = idx - N0;
      int z = i >> 16, rem = i & 65535, n = rem >> 8, k = rem & 255;
      Wb[i] = f2b(pa.W[z][k * 256 + n]);
    } else if (idx < N0 + N1 + N2) {
      int i = idx - N0 - N1;
      int n = i / 224, m = i % 224;
      Wf1T[i] = (n < 200 && m < 200) ? f2b(pa.Wf1[m * 200 + n]) : (u16)0;
    } else if (idx < N0 + N1 + N2 + N3) {
      int i = idx - N0 - N1 - N2;
      int mat = i / 1536, rr = i % 1536;           // 24 rows x 64
      Qb[((size_t)mat * 224 + 200 + rr / 64) * 64 + (rr & 63)] = 0;
    } else {
      int i = idx - N0 - N1 - N2 - N3;
      int mat = i / 512, rr = i % 512;             // 8 rows x 64
      Kb[((size_t)mat * 208 + 200 + rr / 64) * 64 + (rr & 63)] = 0;
    }
  }
}

// ---------------------------------------------------------------------------
// Kernel 1: 9 projections via MFMA.  out = X @ W + bias (bf16 in, f32 acc).
// A-frag: Xb[m][k] k-contig; B-frag: Wb[z][n][k] k-contig — direct 16B loads.
// Scatter: Qb[mat4=bh*4+cq][224][64], Kb[mat=bh*4+ck][208][64], Vb[bh][208][64]
// ---------------------------------------------------------------------------
__global__ __launch_bounds__(256) void proj_mfma(
    const u16* __restrict__ Xb, const u16* __restrict__ Wb, BiasArgs ba,
    u16* __restrict__ Qb, u16* __restrict__ Kb, u16* __restrict__ Vb) {
  const int mb = blockIdx.x, z = blockIdx.y;
  const int row0 = mb * 64;
  const int tid = threadIdx.x;
  const int wv = tid >> 6, ln = tid & 63;
  const int lrow = ln & 15, lk8 = ln >> 4;

  const int zx = (z < 4) ? z : (z == 4 ? 0 : z == 5 ? 2 : z == 6 ? 3 : z == 7 ? 1 : 0);
  const u16* X  = Xb + (size_t)zx * 1638400;
  const u16* Wz = Wb + (size_t)z * 65536;
  const float* bias = ba.Bi[z];

  f32x4 c[4][4];
#pragma unroll
  for (int mt = 0; mt < 4; ++mt)
#pragma unroll
    for (int nt = 0; nt < 4; ++nt) c[mt][nt] = (f32x4){0.f, 0.f, 0.f, 0.f};

#pragma unroll
  for (int ks = 0; ks < 8; ++ks) {
    bf16x8 a[4], bfr[4];
#pragma unroll
    for (int mt = 0; mt < 4; ++mt)
      a[mt] = *(const bf16x8*)&X[(size_t)(row0 + mt * 16 + lrow) * 256 + ks * 32 + lk8 * 8];
#pragma unroll
    for (int nt = 0; nt < 4; ++nt)
      bfr[nt] = *(const bf16x8*)&Wz[(size_t)(wv * 64 + nt * 16 + lrow) * 256 + ks * 32 + lk8 * 8];
#pragma unroll
    for (int mt = 0; mt < 4; ++mt)
#pragma unroll
      for (int nt = 0; nt < 4; ++nt)
        c[mt][nt] = __builtin_amdgcn_mfma_f32_16x16x32_bf16(a[mt], bfr[nt], c[mt][nt], 0, 0, 0);
  }

#pragma unroll
  for (int nt = 0; nt < 4; ++nt) {
    int n = wv * 64 + nt * 16 + lrow;
    float bn = bias[n];
    int h = n >> 6, d = n & 63;
#pragma unroll
    for (int mt = 0; mt < 4; ++mt) {
#pragma unroll
      for (int j = 0; j < 4; ++j) {
        int m = row0 + mt * 16 + lk8 * 4 + j;
        int b = m / 200, l = m - b * 200;
        int bh = b * 4 + h;
        u16 o = f2b(c[mt][nt][j] + bn);
        if (z < 4)      Qb[((size_t)(bh * 4 + z) * 224 + l) * 64 + d] = o;
        else if (z < 8) Kb[((size_t)(bh * 4 + z - 4) * 208 + l) * 64 + d] = o;
        else            Vb[((size_t)bh * 208 + l) * 64 + d] = o;
      }
    }
  }
}

// ---------------------------------------------------------------------------
// Kernel 2: transpose Kb->Ktd [mat][64 d][224 m], Vb->Vt [bh][64 d][224 m],
// zero-padding m 200..223.  640 blocks (512 K-mats + 128 V-mats).
// ---------------------------------------------------------------------------
__global__ __launch_bounds__(256) void transpose_kernel(
    const u16* __restrict__ Kb, const u16* __restrict__ Vb,
    u16* __restrict__ Ktd, u16* __restrict__ Vt) {
  const int t = blockIdx.x;
  const u16* src = (t < 512) ? (Kb + (size_t)t * 208 * 64)
                             : (Vb + (size_t)(t - 512) * 208 * 64);
  u16* dst = (t < 512) ? (Ktd + (size_t)t * 64 * 224)
                       : (Vt + (size_t)(t - 512) * 64 * 224);
  const int tid = threadIdx.x;
  __shared__ u16 tile[64][72];

  for (int m0 = 0; m0 < 224; m0 += 64) {
#pragma unroll
    for (int it = 0; it < 2; ++it) {
      int slot = it * 256 + tid;
      int r = slot >> 3, seg = slot & 7;
      bf16x8 v = {0, 0, 0, 0, 0, 0, 0, 0};
      if (m0 + r < 200) v = *(const bf16x8*)&src[(size_t)(m0 + r) * 64 + seg * 8];
      *(bf16x8*)&tile[r][seg * 8] = v;
    }
    __syncthreads();
#pragma unroll
    for (int it = 0; it < 2; ++it) {
      int slot = it * 256 + tid;
      int dcol = slot >> 3, seg = slot & 7;
      if (m0 + seg * 8 < 224) {
        bf16x8 o;
#pragma unroll
        for (int q = 0; q < 8; ++q) o[q] = (short)tile[seg * 8 + q][dcol];
        *(bf16x8*)&dst[(size_t)dcol * 224 + m0 + seg * 8] = o;
      }
    }
    __syncthreads();
  }
}

// ---------------------------------------------------------------------------
// Kernel 3: KW via MFMA.  KWb[mat][n(256 pad)][64 d] = sum_m Wf1T[n][m]*Ktd[d][m]
// A = Wf1T [n][m] m-contig, B = Ktd [d][m] m-contig.  Rows 200..207 exact 0.
// ---------------------------------------------------------------------------
__global__ __launch_bounds__(256) void kw_mfma(
    const u16* __restrict__ Wf1T, const u16* __restrict__ Ktd,
    u16* __restrict__ KWb) {
  const int mat = blockIdx.x;
  const int tid = threadIdx.x;
  const int wv = tid >> 6, ln = tid & 63;
  const int lrow = ln & 15, lk8 = ln >> 4;
  const u16* Bt = Ktd + (size_t)mat * 64 * 224;

  for (int nt = wv; nt < 13; nt += 4) {
    f32x4 cd0 = {0.f,0.f,0.f,0.f}, cd1 = {0.f,0.f,0.f,0.f};
    f32x4 cd2 = {0.f,0.f,0.f,0.f}, cd3 = {0.f,0.f,0.f,0.f};
#pragma unroll
    for (int ks = 0; ks < 7; ++ks) {
      bf16x8 a = *(const bf16x8*)&Wf1T[(size_t)(nt * 16 + lrow) * 224 + ks * 32 + lk8 * 8];
      bf16x8 b0 = *(const bf16x8*)&Bt[(size_t)(0 * 16 + lrow) * 224 + ks * 32 + lk8 * 8];
      bf16x8 b1 = *(const bf16x8*)&Bt[(size_t)(1 * 16 + lrow) * 224 + ks * 32 + lk8 * 8];
      bf16x8 b2 = *(const bf16x8*)&Bt[(size_t)(2 * 16 + lrow) * 224 + ks * 32 + lk8 * 8];
      bf16x8 b3 = *(const bf16x8*)&Bt[(size_t)(3 * 16 + lrow) * 224 + ks * 32 + lk8 * 8];
      cd0 = __builtin_amdgcn_mfma_f32_16x16x32_bf16(a, b0, cd0, 0, 0, 0);
      cd1 = __builtin_amdgcn_mfma_f32_16x16x32_bf16(a, b1, cd1, 0, 0, 0);
      cd2 = __builtin_amdgcn_mfma_f32_16x16x32_bf16(a, b2, cd2, 0, 0, 0);
      cd3 = __builtin_amdgcn_mfma_f32_16x16x32_bf16(a, b3, cd3, 0, 0, 0);
    }
#pragma unroll
    for (int j = 0; j < 4; ++j) {
      size_t base = ((size_t)mat * 256 + nt * 16 + lk8 * 4 + j) * 64 + lrow;
      KWb[base + 0]  = f2b(cd0[j]);
      KWb[base + 16] = f2b(cd1[j]);
      KWb[base + 32] = f2b(cd2[j]);
      KWb[base + 48] = f2b(cd3[j]);
    }
  }
}

// ---------------------------------------------------------------------------
// Kernel 4: fused MFMA kernel per (bh, 32-l tile):
// energy (Q.KW relu.Wf2) -> channel softmax -> qw -> scores (qw.K) ->
// row softmax -> PV -> ctx (bf16).
// ---------------------------------------------------------------------------
__global__ __launch_bounds__(256) void fused_kernel(
    const u16* __restrict__ Qb, const u16* __restrict__ Kb,
    const u16* __restrict__ KWb, const u16* __restrict__ Vt,
    const float* __restrict__ mask, const float* __restrict__ bf1,
    const float* __restrict__ Wf2, u16* __restrict__ Ctxb) {
  const int lt = blockIdx.x, bh = blockIdx.y;
  const int l0 = lt * 32;
  const int b = bh >> 2, h = bh & 3;
  const int tid = threadIdx.x;
  const int wv = tid >> 6, ln = tid & 63;
  const int lrow = ln & 15, lk8 = ln >> 4;

  __shared__ u16  pb[32 * 232];      // probs bf16 (m-pad 200..231 = 0)
  __shared__ u16  qwl[32 * 264];     // qw bf16 [32 l][264] (k = ck*64+d)
  __shared__ float att[32 * 208];    // scores f32
  __shared__ float El[512];          // energy [32 l][16 c]
  __shared__ float wg[512];          // channel weights
  __shared__ float b1s[256], w2s[256];

  b1s[tid] = (tid < 200) ? bf1[tid] : 0.f;
  w2s[tid] = (tid < 200) ? Wf2[tid] : 0.f;
  __syncthreads();

  // ---- phase E: energy via MFMA.  wave wv owns A rows 32wv..32wv+31 (cq=wv).
  {
    bf16x8 aE[2][2];
#pragma unroll
    for (int mt = 0; mt < 2; ++mt)
#pragma unroll
      for (int ks = 0; ks < 2; ++ks)
        aE[mt][ks] = *(const bf16x8*)&Qb[((size_t)(bh * 4 + wv) * 224 + l0 + mt * 16 + lrow) * 64 + ks * 32 + lk8 * 8];

    float eacc[2][4][4];
#pragma unroll
    for (int mt = 0; mt < 2; ++mt)
#pragma unroll
      for (int ck = 0; ck < 4; ++ck)
#pragma unroll
        for (int j = 0; j < 4; ++j) eacc[mt][ck][j] = 0.f;

#pragma unroll
    for (int ck = 0; ck < 4; ++ck) {
      const u16* KWm = KWb + (size_t)(bh * 4 + ck) * 16384;
#pragma unroll 1
      for (int nt = 0; nt < 13; ++nt) {
        bf16x8 b0 = *(const bf16x8*)&KWm[(nt * 16 + lrow) * 64 + lk8 * 8];
        bf16x8 b1 = *(const bf16x8*)&KWm[(nt * 16 + lrow) * 64 + 32 + lk8 * 8];
        f32x4 c0 = {0.f, 0.f, 0.f, 0.f}, c1 = {0.f, 0.f, 0.f, 0.f};
        c0 = __builtin_amdgcn_mfma_f32_16x16x32_bf16(aE[0][0], b0, c0, 0, 0, 0);
        c0 = __builtin_amdgcn_mfma_f32_16x16x32_bf16(aE[0][1], b1, c0, 0, 0, 0);
        c1 = __builtin_amdgcn_mfma_f32_16x16x32_bf16(aE[1][0], b0, c1, 0, 0, 0);
        c1 = __builtin_amdgcn_mfma_f32_16x16x32_bf16(aE[1][1], b1, c1, 0, 0, 0);
        float b1n = b1s[nt * 16 + lrow];
        float w2n = w2s[nt * 16 + lrow];
#pragma unroll
        for (int j = 0; j < 4; ++j) {
          eacc[0][ck][j] += fmaxf(c0[j] + b1n, 0.f) * w2n;
          eacc[1][ck][j] += fmaxf(c1[j] + b1n, 0.f) * w2n;
        }
      }
    }

#pragma unroll
    for (int mt = 0; mt < 2; ++mt)
#pragma unroll
      for (int ck = 0; ck < 4; ++ck)
#pragma unroll
        for (int j = 0; j < 4; ++j) {
          float v = eacc[mt][ck][j];
          v += __shfl_xor(v, 1);
          v += __shfl_xor(v, 2);
          v += __shfl_xor(v, 4);
          v += __shfl_xor(v, 8);
          if (lrow == 0) {
            int r = (wv * 2 + mt) * 16 + lk8 * 4 + j;   // r = cq*32 + l
            El[(r & 31) * 16 + (r >> 5) * 4 + ck] = v;
          }
        }
  }
  __syncthreads();

  // ---- channel softmax over 16 c per l
#pragma unroll
  for (int it = 0; it < 2; ++it) {
    int l = it * 16 + (tid >> 4), c = tid & 15;
    float e = El[l * 16 + c];
    float mx = e;
    mx = fmaxf(mx, __shfl_xor(mx, 8));
    mx = fmaxf(mx, __shfl_xor(mx, 4));
    mx = fmaxf(mx, __shfl_xor(mx, 2));
    mx = fmaxf(mx, __shfl_xor(mx, 1));
    float ex = __expf(e - mx);
    float s = ex;
    s += __shfl_xor(s, 8);
    s += __shfl_xor(s, 4);
    s += __shfl_xor(s, 2);
    s += __shfl_xor(s, 1);
    wg[l * 16 + c] = ex / s;
  }
  __syncthreads();

  // ---- qw[l][ck*64+d] = sum_cq w[l][cq*4+ck] * q[cq][l][d]   (bf16 out)
  {
    int lq = tid >> 3, d0 = (tid & 7) * 8;
    float qf[4][8];
#pragma unroll
    for (int cq = 0; cq < 4; ++cq) {
      bf16x8 q8 = *(const bf16x8*)&Qb[((size_t)(bh * 4 + cq) * 224 + l0 + lq) * 64 + d0];
#pragma unroll
      for (int j = 0; j < 8; ++j) qf[cq][j] = b2f((u16)q8[j]);
    }
    float wv_[16];
#pragma unroll
    for (int c = 0; c < 16; ++c) wv_[c] = wg[lq * 16 + c];
#pragma unroll
    for (int ck = 0; ck < 4; ++ck) {
      float a[8];
#pragma unroll
      for (int j = 0; j < 8; ++j)
        a[j] = wv_[0 * 4 + ck] * qf[0][j] + wv_[1 * 4 + ck] * qf[1][j] +
               wv_[2 * 4 + ck] * qf[2][j] + wv_[3 * 4 + ck] * qf[3][j];
#pragma unroll
      for (int p = 0; p < 4; ++p) {
        unsigned int pk = f2b(a[2 * p]) | ((unsigned int)f2b(a[2 * p + 1]) << 16);
        *(unsigned int*)&qwl[lq * 264 + ck * 64 + d0 + 2 * p] = pk;
      }
    }
  }
  __syncthreads();

  // ---- scores: wave handles m-tiles wv, wv+4, wv+8, (wv+12)
  for (int mt = wv; mt < 13; mt += 4) {
    f32x4 sc0 = {0.f, 0.f, 0.f, 0.f}, sc1 = {0.f, 0.f, 0.f, 0.f};
#pragma unroll
    for (int ks = 0; ks < 8; ++ks) {
      int ck = ks >> 1, dd = (ks & 1) * 32 + lk8 * 8;
      const u16* Km = Kb + (size_t)(bh * 4 + ck) * 208 * 64;
      bf16x8 bK = *(const bf16x8*)&Km[(mt * 16 + lrow) * 64 + dd];
      bf16x8 a0 = *(const bf16x8*)&qwl[lrow * 264 + ck * 64 + dd];
      bf16x8 a1 = *(const bf16x8*)&qwl[(16 + lrow) * 264 + ck * 64 + dd];
      sc0 = __builtin_amdgcn_mfma_f32_16x16x32_bf16(a0, bK, sc0, 0, 0, 0);
      sc1 = __builtin_amdgcn_mfma_f32_16x16x32_bf16(a1, bK, sc1, 0, 0, 0);
    }
    int m = mt * 16 + lrow;
    int gm = (m > 199) ? 199 : m;
#pragma unroll
    for (int j = 0; j < 4; ++j) {
      int la = lk8 * 4 + j;
      int gla = l0 + la; if (gla > 199) gla = 199;
      int lb = 16 + lk8 * 4 + j;
      int glb = l0 + lb; if (glb > 199) glb = 199;
      att[la * 208 + m] = sc0[j] * SCALE_ + mask[(size_t)gla * 200 + gm];
      att[lb * 208 + m] = sc1[j] * SCALE_ + mask[(size_t)glb * 200 + gm];
    }
  }
  __syncthreads();

  // ---- row softmax over m (exclude m>=200), write pb bf16 [32][232]
#pragma unroll
  for (int it = 0; it < 2; ++it) {
    int l = it * 16 + (tid >> 4), j = tid & 15;
    float mx = -3.0e38f;
    for (int m = j; m < 200; m += 16) mx = fmaxf(mx, att[l * 208 + m]);
    mx = fmaxf(mx, __shfl_xor(mx, 8));
    mx = fmaxf(mx, __shfl_xor(mx, 4));
    mx = fmaxf(mx, __shfl_xor(mx, 2));
    mx = fmaxf(mx, __shfl_xor(mx, 1));
    float s = 0.f;
    for (int m = j; m < 200; m += 16) {
      float ex = __expf(att[l * 208 + m] - mx);
      att[l * 208 + m] = ex;
      s += ex;
    }
    s += __shfl_xor(s, 8);
    s += __shfl_xor(s, 4);
    s += __shfl_xor(s, 2);
    s += __shfl_xor(s, 1);
    float rinv = 1.f / s;
    for (int m = j; m < 200; m += 16) pb[l * 232 + m] = f2b(att[l * 208 + m] * rinv);
    for (int m = 200 + j; m < 232; m += 16) pb[l * 232 + m] = 0;
  }
  __syncthreads();

  // ---- PV: wave owns d-tile wv (16 d).  K = 224 (7 steps), pad probs = 0.
  {
    const u16* Vb = Vt + (size_t)bh * 64 * 224;
    f32x4 pc0 = {0.f, 0.f, 0.f, 0.f}, pc1 = {0.f, 0.f, 0.f, 0.f};
#pragma unroll
    for (int ks = 0; ks < 7; ++ks) {
      int mm = ks * 32 + lk8 * 8;
      bf16x8 a0 = *(const bf16x8*)&pb[lrow * 232 + mm];
      bf16x8 a1 = *(const bf16x8*)&pb[(16 + lrow) * 232 + mm];
      bf16x8 bV = *(const bf16x8*)&Vb[(wv * 16 + lrow) * 224 + mm];
      pc0 = __builtin_amdgcn_mfma_f32_16x16x32_bf16(a0, bV, pc0, 0, 0, 0);
      pc1 = __builtin_amdgcn_mfma_f32_16x16x32_bf16(a1, bV, pc1, 0, 0, 0);
    }
#pragma unroll
    for (int j = 0; j < 4; ++j) {
      int la = lk8 * 4 + j, lb = 16 + lk8 * 4 + j;
      int gla = l0 + la, glb = l0 + lb;
      int d = h * 64 + wv * 16 + lrow;
      if (gla < 200) Ctxb[((size_t)b * 200 + gla) * 256 + d] = f2b(pc0[j]);
      if (glb < 200) Ctxb[((size_t)b * 200 + glb) * 256 + d] = f2b(pc1[j]);
    }
  }
}

// ---------------------------------------------------------------------------
// Kernel 5: out-proj via MFMA + residual + LayerNorm.  64 rows per block.
// A = Ctxb[m][k], B = WdT[n][k] (Wb slot 9).
// ---------------------------------------------------------------------------
__global__ __launch_bounds__(256) void out_ln_kernel(
    const u16* __restrict__ Ctxb, const u16* __restrict__ WdT,
    const float* __restrict__ bd, const float* __restrict__ input,
    const float* __restrict__ gamma, const float* __restrict__ beta,
    float* __restrict__ out) {
  const int row0 = blockIdx.x * 64;
  const int tid = threadIdx.x;
  const int wv = tid >> 6, ln = tid & 63;
  const int lrow = ln & 15, lk8 = ln >> 4;

  __shared__ float redA[64][65];
  __shared__ float redB[64][65];
  __shared__ float mus[64], rsd[64];

  f32x4 c[4][4];
#pragma unroll
  for (int mt = 0; mt < 4; ++mt)
#pragma unroll
    for (int nt = 0; nt < 4; ++nt) c[mt][nt] = (f32x4){0.f, 0.f, 0.f, 0.f};

#pragma unroll
  for (int ks = 0; ks < 8; ++ks) {
    bf16x8 a[4], bfr[4];
#pragma unroll
    for (int mt = 0; mt < 4; ++mt)
      a[mt] = *(const bf16x8*)&Ctxb[(size_t)(row0 + mt * 16 + lrow) * 256 + ks * 32 + lk8 * 8];
#pragma unroll
    for (int nt = 0; nt < 4; ++nt)
      bfr[nt] = *(const bf16x8*)&WdT[(size_t)(wv * 64 + nt * 16 + lrow) * 256 + ks * 32 + lk8 * 8];
#pragma unroll
    for (int mt = 0; mt < 4; ++mt)
#pragma unroll
      for (int nt = 0; nt < 4; ++nt)
        c[mt][nt] = __builtin_amdgcn_mfma_f32_16x16x32_bf16(a[mt], bfr[nt], c[mt][nt], 0, 0, 0);
  }

  float s1[4][4], s2[4][4];
#pragma unroll
  for (int mt = 0; mt < 4; ++mt)
#pragma unroll
    for (int j = 0; j < 4; ++j) { s1[mt][j] = 0.f; s2[mt][j] = 0.f; }

#pragma unroll
  for (int nt = 0; nt < 4; ++nt) {
    int n = wv * 64 + nt * 16 + lrow;
    float bdn = bd[n];
#pragma unroll
    for (int mt = 0; mt < 4; ++mt) {
      int mbase = row0 + mt * 16 + lk8 * 4;
#pragma unroll
      for (int j = 0; j < 4; ++j) {
        float x = c[mt][nt][j] + bdn + input[(size_t)(mbase + j) * 256 + n];
        c[mt][nt][j] = x;
        s1[mt][j] += x;
        s2[mt][j] += x * x;
      }
    }
  }
#pragma unroll
  for (int mt = 0; mt < 4; ++mt)
#pragma unroll
    for (int j = 0; j < 4; ++j) {
      redA[mt * 16 + lk8 * 4 + j][wv * 16 + lrow] = s1[mt][j];
      redB[mt * 16 + lk8 * 4 + j][wv * 16 + lrow] = s2[mt][j];
    }
  __syncthreads();
  if (tid < 64) {
    float a = 0.f, b2 = 0.f;
#pragma unroll 8
    for (int i = 0; i < 64; ++i) { a += redA[tid][i]; b2 += redB[tid][i]; }
    float mu = a * (1.f / 256.f);
    float var = b2 * (1.f / 256.f) - mu * mu;
    mus[tid] = mu;
    rsd[tid] = rsqrtf(var + EPS_);
  }
  __syncthreads();
#pragma unroll
  for (int nt = 0; nt < 4; ++nt) {
    int n = wv * 64 + nt * 16 + lrow;
    float g = gamma[n], be = beta[n];
#pragma unroll
    for (int mt = 0; mt < 4; ++mt) {
#pragma unroll
      for (int j = 0; j < 4; ++j) {
        int r = mt * 16 + lk8 * 4 + j;
        out[(size_t)(row0 + r) * 256 + n] = (c[mt][nt][j] - mus[r]) * rsd[r] * g + be;
      }
    }
  }
}

// ---------------------------------------------------------------------------
extern "C" void kernel_launch(void* const* d_in, const int* in_sizes, int n_in,
                              void* d_out, int out_size, void* d_ws, size_t ws_size,
                              hipStream_t stream) {
  const float* input = (const float*)d_in[0];
  const float* attrt = (const float*)d_in[1];   // (F,B,L,1,H)
  const float* pos   = (const float*)d_in[2];
  const float* mask  = (const float*)d_in[3];
  const float* Wq  = (const float*)d_in[4];   const float* bq  = (const float*)d_in[5];
  const float* Wk  = (const float*)d_in[6];   const float* bk  = (const float*)d_in[7];
  const float* Wv  = (const float*)d_in[8];   const float* bv  = (const float*)d_in[9];
  const float* Wqp = (const float*)d_in[10];  const float* bqp = (const float*)d_in[11];
  const float* Wkp = (const float*)d_in[12];  const float* bkp = (const float*)d_in[13];
  const float* Wq_a = (const float*)d_in[16]; const float* bq_a = (const float*)d_in[17];
  const float* Wk_a = (const float*)d_in[18]; const float* bk_a = (const float*)d_in[19];
  const float* Wf1 = (const float*)d_in[22];  const float* bf1 = (const float*)d_in[23];
  const float* Wf2 = (const float*)d_in[24];
  const float* Wd  = (const float*)d_in[26];  const float* bd  = (const float*)d_in[27];
  const float* gamma = (const float*)d_in[28]; const float* beta = (const float*)d_in[29];

  const float* attr0 = attrt;
  const float* attr1 = attrt + (size_t)B_ * L_ * H_;

  u16* wsu  = (u16*)d_ws;
  u16* Xb   = wsu;                    // 6,553,600
  u16* Wb   = Xb + 6553600;           //   655,360 (10 x 256 x 256)
  u16* Wf1T = Wb + 655360;            //    46,592 (208 x 224)
  u16* Qb   = Wf1T + 46592;           // 7,340,032 (512 x 224 x 64)
  u16* Kb   = Qb + 7340032;           // 6,815,744 (512 x 208 x 64)
  u16* Vb   = Kb + 6815744;           // 1,703,936 (128 x 208 x 64)
  u16* Ktd  = Vb + 1703936;           // 7,340,032 (512 x 64 x 224)
  u16* Vt   = Ktd + 7340032;          // 1,835,008 (128 x 64 x 224)
  u16* KWb  = Vt + 1835008;           // 8,388,608 (512 x 256 x 64)
  u16* Ctxb = KWb + 8388608;          // 1,638,400 (6400 x 256)
  // total 42,317,312 u16 = 84.6 MiB

  PrepArgs pp;
  pp.X[0] = input; pp.X[1] = pos; pp.X[2] = attr0; pp.X[3] = attr1;
  pp.W[0] = Wq;  pp.W[1] = Wqp; pp.W[2] = Wq_a; pp.W[3] = Wq_a + 65536;
  pp.W[4] = Wk;  pp.W[5] = Wk_a; pp.W[6] = Wk_a + 65536; pp.W[7] = Wkp;
  pp.W[8] = Wv;  pp.W[9] = Wd;
  pp.Wf1 = Wf1;

  BiasArgs ba;
  ba.Bi[0] = bq;  ba.Bi[1] = bqp;  ba.Bi[2] = bq_a; ba.Bi[3] = bq_a + 256;
  ba.Bi[4] = bk;  ba.Bi[5] = bk_a; ba.Bi[6] = bk_a + 256; ba.Bi[7] = bkp;
  ba.Bi[8] = bv;

  prep_kernel<<<dim3(4096), dim3(256), 0, stream>>>(pp, Xb, Wb, Wf1T, Qb, Kb);
  proj_mfma<<<dim3(100, 9), dim3(256), 0, stream>>>(Xb, Wb, ba, Qb, Kb, Vb);
  transpose_kernel<<<dim3(640), dim3(256), 0, stream>>>(Kb, Vb, Ktd, Vt);
  kw_mfma<<<dim3(512), dim3(256), 0, stream>>>(Wf1T, Ktd, KWb);
  fused_kernel<<<dim3(7, 128), dim3(256), 0, stream>>>(Qb, Kb, KWb, Vt,
                                                       mask, bf1, Wf2, Ctxb);
  out_ln_kernel<<<dim3(100), dim3(256), 0, stream>>>(Ctxb, Wb + 9 * 65536, bd,
                                                     input, gamma, beta,
                                                     (float*)d_out);
}